// Round 3
// baseline (1030.885 us; speedup 1.0000x reference)
//
#include <hip/hip_runtime.h>

#define NEG_SLOPE 0.2f

__device__ __forceinline__ float lrelu(float x) { return x > 0.f ? x : NEG_SLOPE * x; }

// ---------------- h0 = relu(x @ Wp + bp) : [N,16]@[16,64] ----------------
__global__ void proj_kernel(const float* __restrict__ x, const float* __restrict__ Wp,
                            const float* __restrict__ bp, float* __restrict__ h, int n_nodes) {
  int idx = blockIdx.x * blockDim.x + threadIdx.x;
  int n = idx >> 6, c = idx & 63;
  if (n >= n_nodes) return;
  float acc = bp[c];
#pragma unroll
  for (int k = 0; k < 16; ++k) acc += x[n * 16 + k] * Wp[k * 64 + c];
  h[n * 64 + c] = fmaxf(acc, 0.f);
}

// ---------------- CSR build (by destination), self-loop first ----------------
__global__ void init_deg_kernel(int* __restrict__ deg, int n) {
  int i = blockIdx.x * blockDim.x + threadIdx.x;
  if (i < n) deg[i] = 1;  // self loop
}

__global__ void hist_kernel(const int* __restrict__ dst, int* __restrict__ deg, int e) {
  int i = blockIdx.x * blockDim.x + threadIdx.x;
  if (i < e) atomicAdd(&deg[dst[i]], 1);
}

// single block of 1024 threads, n ~ 50k
__global__ void scan_kernel(const int* __restrict__ deg, int* __restrict__ rowp, int n) {
  __shared__ int sums[1024];
  int tid = threadIdx.x;
  int chunk = (n + 1023) >> 10;
  int start = tid * chunk;
  int end = min(start + chunk, n);
  int local = 0;
  for (int i = start; i < end; ++i) local += deg[i];
  sums[tid] = local;
  __syncthreads();
  for (int off = 1; off < 1024; off <<= 1) {
    int v = 0;
    if (tid >= off) v = sums[tid - off];
    __syncthreads();
    if (tid >= off) sums[tid] += v;
    __syncthreads();
  }
  int prefix = (tid == 0) ? 0 : sums[tid - 1];
  for (int i = start; i < end; ++i) {
    rowp[i] = prefix;
    prefix += deg[i];
  }
  if (tid == 1023) rowp[n] = sums[1023];
}

__global__ void init_csr_kernel(const int* __restrict__ rowp, int* __restrict__ cnt,
                                int* __restrict__ col, int n) {
  int i = blockIdx.x * blockDim.x + threadIdx.x;
  if (i < n) {
    cnt[i] = 1;          // slot 0 taken by self loop
    col[rowp[i]] = i;    // self loop src = i
  }
}

__global__ void scatter_kernel(const int* __restrict__ src, const int* __restrict__ dst,
                               const int* __restrict__ rowp, int* __restrict__ cnt,
                               int* __restrict__ col, int e) {
  int i = blockIdx.x * blockDim.x + threadIdx.x;
  if (i < e) {
    int d = dst[i];
    int pos = rowp[d] + atomicAdd(&cnt[d], 1);
    col[pos] = src[i];
  }
}

// ---------------- hw = h @ W (64->256) + fused attention logits ----------------
// W column t held in 64 VGPRs; 64 h-rows staged in LDS; al_s/al_d via 64-lane shfl reduce.
#define HWROWS 64
__global__ __launch_bounds__(256) void hw_kernel(const float* __restrict__ h, const float* __restrict__ W,
                                                 const float* __restrict__ a_s, const float* __restrict__ a_d,
                                                 float* __restrict__ hw, float* __restrict__ al_s,
                                                 float* __restrict__ al_d, int n_nodes) {
  __shared__ float hs[HWROWS * 64];
  int t = threadIdx.x;
  int lane = t & 63, wave = t >> 6;
  int n0 = blockIdx.x * HWROWS;

  float wreg[64];
#pragma unroll
  for (int k = 0; k < 64; ++k) wreg[k] = W[k * 256 + t];
  float as_t = a_s[t];
  float ad_t = a_d[t];

  int rmax = min(HWROWS, n_nodes - n0);
  int lim = rmax * 64;
  for (int i = t; i < HWROWS * 64; i += 256) hs[i] = (i < lim) ? h[n0 * 64 + i] : 0.f;
  __syncthreads();

  for (int r = 0; r < rmax; ++r) {
    float acc = 0.f;
#pragma unroll
    for (int k4 = 0; k4 < 16; ++k4) {
      float4 hv = *(const float4*)&hs[r * 64 + k4 * 4];
      acc += hv.x * wreg[4 * k4 + 0];
      acc += hv.y * wreg[4 * k4 + 1];
      acc += hv.z * wreg[4 * k4 + 2];
      acc += hv.w * wreg[4 * k4 + 3];
    }
    int n = n0 + r;
    hw[n * 256 + t] = acc;
    float vs = acc * as_t;
    float vd = acc * ad_t;
#pragma unroll
    for (int off = 32; off; off >>= 1) {
      vs += __shfl_xor(vs, off);
      vd += __shfl_xor(vd, off);
    }
    if (lane == 0) {
      al_s[n * 4 + wave] = vs;
      al_d[n * 4 + wave] = vd;
    }
  }
}

// ---------------- per-node softmax + gather-aggregate; block(256) = one node ----------------
__global__ __launch_bounds__(256) void gat_agg(const int* __restrict__ rowp, const int* __restrict__ col,
                                               const float* __restrict__ alS, const float* __restrict__ alD,
                                               const float* __restrict__ hw, const float* __restrict__ bias,
                                               float* __restrict__ hout, int n_nodes) {
  int n = blockIdx.x;
  int t = threadIdx.x;
  int lane = t & 63, wave = t >> 6;
  int base = rowp[n];
  int deg = rowp[n + 1] - base;

  float ald0 = alD[n * 4 + 0], ald1 = alD[n * 4 + 1], ald2 = alD[n * 4 + 2], ald3 = alD[n * 4 + 3];

  // phase 1: per-head max of leaky_relu(al_s[src] + al_d[n])
  float m0 = -1e30f, m1 = -1e30f, m2 = -1e30f, m3 = -1e30f;
  for (int i = t; i < deg; i += 256) {
    int s = col[base + i];
    float4 a4 = *(const float4*)(alS + s * 4);
    m0 = fmaxf(m0, lrelu(a4.x + ald0));
    m1 = fmaxf(m1, lrelu(a4.y + ald1));
    m2 = fmaxf(m2, lrelu(a4.z + ald2));
    m3 = fmaxf(m3, lrelu(a4.w + ald3));
  }
#pragma unroll
  for (int off = 32; off; off >>= 1) {
    m0 = fmaxf(m0, __shfl_xor(m0, off));
    m1 = fmaxf(m1, __shfl_xor(m1, off));
    m2 = fmaxf(m2, __shfl_xor(m2, off));
    m3 = fmaxf(m3, __shfl_xor(m3, off));
  }
  __shared__ float red[4][4];
  if (lane == 0) { red[wave][0] = m0; red[wave][1] = m1; red[wave][2] = m2; red[wave][3] = m3; }
  __syncthreads();
  m0 = fmaxf(fmaxf(red[0][0], red[1][0]), fmaxf(red[2][0], red[3][0]));
  m1 = fmaxf(fmaxf(red[0][1], red[1][1]), fmaxf(red[2][1], red[3][1]));
  m2 = fmaxf(fmaxf(red[0][2], red[1][2]), fmaxf(red[2][2], red[3][2]));
  m3 = fmaxf(fmaxf(red[0][3], red[1][3]), fmaxf(red[2][3], red[3][3]));
  __syncthreads();

  // phase 2: per-head sum of exp(e - m)
  float s0 = 0.f, s1 = 0.f, s2 = 0.f, s3 = 0.f;
  for (int i = t; i < deg; i += 256) {
    int s = col[base + i];
    float4 a4 = *(const float4*)(alS + s * 4);
    s0 += expf(lrelu(a4.x + ald0) - m0);
    s1 += expf(lrelu(a4.y + ald1) - m1);
    s2 += expf(lrelu(a4.z + ald2) - m2);
    s3 += expf(lrelu(a4.w + ald3) - m3);
  }
#pragma unroll
  for (int off = 32; off; off >>= 1) {
    s0 += __shfl_xor(s0, off);
    s1 += __shfl_xor(s1, off);
    s2 += __shfl_xor(s2, off);
    s3 += __shfl_xor(s3, off);
  }
  if (lane == 0) { red[wave][0] = s0; red[wave][1] = s1; red[wave][2] = s2; red[wave][3] = s3; }
  __syncthreads();
  s0 = red[0][0] + red[1][0] + red[2][0] + red[3][0];
  s1 = red[0][1] + red[1][1] + red[2][1] + red[3][1];
  s2 = red[0][2] + red[1][2] + red[2][2] + red[3][2];
  s3 = red[0][3] + red[1][3] + red[2][3] + red[3][3];

  float mh   = wave == 0 ? m0 : wave == 1 ? m1 : wave == 2 ? m2 : m3;
  float sh   = wave == 0 ? s0 : wave == 1 ? s1 : wave == 2 ? s2 : s3;
  float aldh = wave == 0 ? ald0 : wave == 1 ? ald1 : wave == 2 ? ald2 : ald3;
  float inv = 1.f / sh;

  // phase 3: acc[t] = sum_edges alpha(e, head) * hw[src][t]   (t = head*64 + c)
  float acc = 0.f;
#pragma unroll 4
  for (int i = 0; i < deg; ++i) {
    int s = col[base + i];                 // same addr across block -> broadcast
    float as_h = alS[s * 4 + wave];        // same addr per wave -> broadcast
    float w = expf(lrelu(as_h + aldh) - mh) * inv;
    acc += w * hw[s * 256 + t];            // coalesced 256B/wave
  }

  __shared__ float sacc[256];
  sacc[t] = acc;
  __syncthreads();
  if (t < 64) {
    float v = 0.25f * (sacc[t] + sacc[t + 64] + sacc[t + 128] + sacc[t + 192]) + bias[t];
    hout[n * 64 + t] = fmaxf(v, 0.f);
  }
}

// ---------------- global mean pool (batch is sorted) ----------------
__global__ void pool_kernel(const float* __restrict__ h, const int* __restrict__ batch,
                            float* __restrict__ pool, float* __restrict__ pcnt, int n_nodes) {
  int c = threadIdx.x;  // 64 threads
  int n0 = blockIdx.x * 64;
  int n1 = min(n0 + 64, n_nodes);
  float acc = 0.f;
  int run = 0;
  int gcur = batch[n0];
  for (int n = n0; n < n1; ++n) {
    int g = batch[n];
    if (g != gcur) {
      atomicAdd(&pool[gcur * 64 + c], acc);
      if (c == 0) atomicAdd(&pcnt[gcur], (float)run);
      acc = 0.f; run = 0; gcur = g;
    }
    acc += h[n * 64 + c];
    ++run;
  }
  atomicAdd(&pool[gcur * 64 + c], acc);
  if (c == 0) atomicAdd(&pcnt[gcur], (float)run);
}

// ---------------- out = (pool/cnt) @ Wo + bo : [G,64]@[64,32] ----------------
__global__ void out_kernel(const float* __restrict__ pool, const float* __restrict__ pcnt,
                           const float* __restrict__ Wo, const float* __restrict__ bo,
                           float* __restrict__ out, int g_total) {
  int idx = blockIdx.x * blockDim.x + threadIdx.x;
  if (idx >= g_total * 32) return;
  int g = idx >> 5, d = idx & 31;
  float inv = 1.f / fmaxf(pcnt[g], 1.f);
  float acc = bo[d];
#pragma unroll
  for (int c = 0; c < 64; ++c) acc += (pool[g * 64 + c] * inv) * Wo[c * 32 + d];
  out[idx] = acc;
}

extern "C" void kernel_launch(void* const* d_in, const int* in_sizes, int n_in,
                              void* d_out, int out_size, void* d_ws, size_t ws_size,
                              hipStream_t stream) {
  const float* x     = (const float*)d_in[0];
  const int*   ei    = (const int*)d_in[1];
  const int*   batch = (const int*)d_in[2];
  const float* Wp    = (const float*)d_in[3];
  const float* bp    = (const float*)d_in[4];
  const float* Wo    = (const float*)d_in[5];
  const float* bo    = (const float*)d_in[6];
  const float* Wl[3]  = {(const float*)d_in[7],  (const float*)d_in[11], (const float*)d_in[15]};
  const float* Asl[3] = {(const float*)d_in[8],  (const float*)d_in[12], (const float*)d_in[16]};
  const float* Adl[3] = {(const float*)d_in[9],  (const float*)d_in[13], (const float*)d_in[17]};
  const float* Bl[3]  = {(const float*)d_in[10], (const float*)d_in[14], (const float*)d_in[18]};

  const int N = in_sizes[0] / 16;   // 50000
  const int E = in_sizes[1] / 2;    // 800000
  const int G = out_size / 32;      // 64
  const int* src = ei;
  const int* dst = ei + E;

  // workspace carve (256B aligned)
  char* ws = (char*)d_ws;
  size_t off = 0;
  auto take = [&](size_t bytes) -> void* {
    void* p = ws + off;
    off = (off + bytes + 255) & ~(size_t)255;
    return p;
  };
  float* h_a  = (float*)take((size_t)N * 64 * 4);
  float* h_b  = (float*)take((size_t)N * 64 * 4);
  float* hw   = (float*)take((size_t)N * 256 * 4);
  float* alS  = (float*)take((size_t)N * 4 * 4);
  float* alD  = (float*)take((size_t)N * 4 * 4);
  int*   deg  = (int*)take((size_t)N * 4);
  int*   cnt  = (int*)take((size_t)N * 4);
  int*   rowp = (int*)take((size_t)(N + 1) * 4);
  int*   col  = (int*)take((size_t)(E + N) * 4);
  float* pool = (float*)take((size_t)G * 64 * 4);
  float* pcnt = (float*)take((size_t)G * 4);
  (void)ws_size; (void)n_in;

  // CSR build
  init_deg_kernel<<<(N + 255) / 256, 256, 0, stream>>>(deg, N);
  hist_kernel<<<(E + 255) / 256, 256, 0, stream>>>(dst, deg, E);
  scan_kernel<<<1, 1024, 0, stream>>>(deg, rowp, N);
  init_csr_kernel<<<(N + 255) / 256, 256, 0, stream>>>(rowp, cnt, col, N);
  scatter_kernel<<<(E + 255) / 256, 256, 0, stream>>>(src, dst, rowp, cnt, col, E);

  // input projection
  proj_kernel<<<((size_t)N * 64 + 255) / 256, 256, 0, stream>>>(x, Wp, bp, h_a, N);

  // 3 GAT layers
  const float* hin = h_a;
  float* hout = h_b;
  for (int l = 0; l < 3; ++l) {
    hw_kernel<<<(N + HWROWS - 1) / HWROWS, 256, 0, stream>>>(hin, Wl[l], Asl[l], Adl[l], hw, alS, alD, N);
    gat_agg<<<N, 256, 0, stream>>>(rowp, col, alS, alD, hw, Bl[l], hout, N);
    const float* tmp = hout;
    hout = (float*)hin;
    hin = tmp;
  }

  // pooling + output projection
  hipMemsetAsync(pool, 0, (size_t)G * 64 * 4, stream);
  hipMemsetAsync(pcnt, 0, (size_t)G * 4, stream);
  pool_kernel<<<(N + 63) / 64, 64, 0, stream>>>(hin, batch, pool, pcnt, N);
  out_kernel<<<(G * 32 + 255) / 256, 256, 0, stream>>>(pool, pcnt, Wo, bo, (float*)d_out, G);
}

// Round 4
// 810.558 us; speedup vs baseline: 1.2718x; 1.2718x over previous
//
#include <hip/hip_runtime.h>

#define NEG_SLOPE 0.2f

__device__ __forceinline__ float lrelu(float x) { return x > 0.f ? x : NEG_SLOPE * x; }

// ---------------- h0 = relu(x @ Wp + bp) : [N,16]@[16,64] ----------------
__global__ void proj_kernel(const float* __restrict__ x, const float* __restrict__ Wp,
                            const float* __restrict__ bp, float* __restrict__ h, int n_nodes) {
  int idx = blockIdx.x * blockDim.x + threadIdx.x;
  int n = idx >> 6, c = idx & 63;
  if (n >= n_nodes) return;
  float acc = bp[c];
#pragma unroll
  for (int k = 0; k < 16; ++k) acc += x[n * 16 + k] * Wp[k * 64 + c];
  h[n * 64 + c] = fmaxf(acc, 0.f);
}

// ---------------- CSR build (by destination), self-loop first ----------------
__global__ void init_deg_kernel(int* __restrict__ deg, int n) {
  int i = blockIdx.x * blockDim.x + threadIdx.x;
  if (i < n) deg[i] = 1;  // self loop
}

__global__ void hist_kernel(const int* __restrict__ dst, int* __restrict__ deg, int e) {
  int i = blockIdx.x * blockDim.x + threadIdx.x;
  if (i < e) atomicAdd(&deg[dst[i]], 1);
}

// single block of 1024 threads, n ~ 50k
__global__ void scan_kernel(const int* __restrict__ deg, int* __restrict__ rowp, int n) {
  __shared__ int sums[1024];
  int tid = threadIdx.x;
  int chunk = (n + 1023) >> 10;
  int start = tid * chunk;
  int end = min(start + chunk, n);
  int local = 0;
  for (int i = start; i < end; ++i) local += deg[i];
  sums[tid] = local;
  __syncthreads();
  for (int off = 1; off < 1024; off <<= 1) {
    int v = 0;
    if (tid >= off) v = sums[tid - off];
    __syncthreads();
    if (tid >= off) sums[tid] += v;
    __syncthreads();
  }
  int prefix = (tid == 0) ? 0 : sums[tid - 1];
  for (int i = start; i < end; ++i) {
    rowp[i] = prefix;
    prefix += deg[i];
  }
  if (tid == 1023) rowp[n] = sums[1023];
}

__global__ void init_csr_kernel(const int* __restrict__ rowp, int* __restrict__ cnt,
                                int* __restrict__ col, int* __restrict__ row_of, int n) {
  int i = blockIdx.x * blockDim.x + threadIdx.x;
  if (i < n) {
    cnt[i] = 1;           // slot 0 taken by self loop
    int p = rowp[i];
    col[p] = i;           // self loop src = i
    row_of[p] = i;
  }
}

__global__ void scatter_kernel(const int* __restrict__ src, const int* __restrict__ dst,
                               const int* __restrict__ rowp, int* __restrict__ cnt,
                               int* __restrict__ col, int* __restrict__ row_of, int e) {
  int i = blockIdx.x * blockDim.x + threadIdx.x;
  if (i < e) {
    int d = dst[i];
    int pos = rowp[d] + atomicAdd(&cnt[d], 1);
    col[pos] = src[i];
    row_of[pos] = d;
  }
}

// ---------------- fold a_src/a_dst into W: Wa[l][k][o] (o<4: src head o; o>=4: dst head o-4) ----
__global__ void prep_wa3(const float* __restrict__ W0, const float* __restrict__ as0, const float* __restrict__ ad0,
                         const float* __restrict__ W1, const float* __restrict__ as1, const float* __restrict__ ad1,
                         const float* __restrict__ W2, const float* __restrict__ as2, const float* __restrict__ ad2,
                         float* __restrict__ Wa) {
  int l = blockIdx.x;
  const float* W  = l == 0 ? W0  : l == 1 ? W1  : W2;
  const float* as = l == 0 ? as0 : l == 1 ? as1 : as2;
  const float* ad = l == 0 ? ad0 : l == 1 ? ad1 : ad2;
  int t = threadIdx.x;          // 256 threads
  int k = t >> 2, h = t & 3;
  float ss = 0.f, sd = 0.f;
  for (int c = 0; c < 64; ++c) {
    float w = W[k * 256 + h * 64 + c];
    ss += w * as[h * 64 + c];
    sd += w * ad[h * 64 + c];
  }
  Wa[l * 512 + k * 8 + h] = ss;
  Wa[l * 512 + k * 8 + 4 + h] = sd;
}

// ---------------- hw = h @ W (64->256) + attention logits via folded Wa ----------------
#define HWROWS 64
__global__ __launch_bounds__(256) void hw_kernel(const float* __restrict__ h, const float* __restrict__ W,
                                                 const float* __restrict__ Wa,
                                                 float* __restrict__ hw, float* __restrict__ al_s,
                                                 float* __restrict__ al_d, int n_nodes) {
  __shared__ float hs[HWROWS][68];   // +4 pad: conflict-free for both access patterns
  __shared__ float was[64][8];
  int t = threadIdx.x;
  int n0 = blockIdx.x * HWROWS;

  float wreg[64];
#pragma unroll
  for (int k = 0; k < 64; ++k) wreg[k] = W[k * 256 + t];
  for (int i = t; i < 512; i += 256) was[i >> 3][i & 7] = Wa[i];

  int rmax = min(HWROWS, n_nodes - n0);
  for (int i = t; i < HWROWS * 64; i += 256) {
    int r = i >> 6, c = i & 63;
    hs[r][c] = (r < rmax) ? h[(n0 + r) * 64 + c] : 0.f;
  }
  __syncthreads();

  for (int r = 0; r < rmax; ++r) {
    float acc = 0.f;
#pragma unroll
    for (int k4 = 0; k4 < 16; ++k4) {
      float4 hv = *(const float4*)&hs[r][4 * k4];
      acc += hv.x * wreg[4 * k4 + 0];
      acc += hv.y * wreg[4 * k4 + 1];
      acc += hv.z * wreg[4 * k4 + 2];
      acc += hv.w * wreg[4 * k4 + 3];
    }
    hw[(n0 + r) * 256 + t] = acc;
  }

  // logits: 512 tasks (64 rows x 8 outputs), 2 per thread, 64-length LDS dots
#pragma unroll
  for (int j = 0; j < 2; ++j) {
    int task = t + j * 256;
    int r = task >> 3, o = task & 7;
    if (r < rmax) {
      float acc = 0.f;
#pragma unroll 8
      for (int k = 0; k < 64; ++k) acc += hs[r][k] * was[k][o];
      int n = n0 + r;
      if (o < 4) al_s[n * 4 + o] = acc;
      else       al_d[n * 4 + (o - 4)] = acc;
    }
  }
}

// ---------------- per-edge unnormalized attention weight (4 heads) ----------------
__global__ void edge_ex_kernel(const int* __restrict__ col, const int* __restrict__ row_of,
                               const float* __restrict__ alS, const float* __restrict__ alD,
                               float* __restrict__ ex, int ecnt) {
  int p = blockIdx.x * blockDim.x + threadIdx.x;
  if (p >= ecnt) return;
  int s = col[p], d = row_of[p];
  float4 as = *(const float4*)(alS + s * 4);
  float4 ad = *(const float4*)(alD + d * 4);
  float4 e;
  e.x = expf(lrelu(as.x + ad.x));
  e.y = expf(lrelu(as.y + ad.y));
  e.z = expf(lrelu(as.z + ad.z));
  e.w = expf(lrelu(as.w + ad.w));
  *(float4*)(ex + p * 4) = e;
}

// ---------------- single-pass aggregate: out = (sum ex*hw[s]) / (sum ex) ----------------
__global__ __launch_bounds__(256) void gat_agg(const int* __restrict__ rowp, const int* __restrict__ col,
                                               const float* __restrict__ ex, const float* __restrict__ hw,
                                               const float* __restrict__ bias, float* __restrict__ hout,
                                               int n_nodes) {
  int n = blockIdx.x;
  int t = threadIdx.x;
  int wave = t >> 6;
  int base = rowp[n];
  int deg = rowp[n + 1] - base;

  float acc = 0.f, denom = 0.f;
#pragma unroll 4
  for (int i = 0; i < deg; ++i) {
    int s = col[base + i];                    // broadcast
    float w = ex[(base + i) * 4 + wave];      // broadcast per wave
    denom += w;
    acc += w * hw[s * 256 + t];               // coalesced 1KB/edge
  }
  acc /= denom;

  __shared__ float sacc[256];
  sacc[t] = acc;
  __syncthreads();
  if (t < 64) {
    float v = 0.25f * (sacc[t] + sacc[t + 64] + sacc[t + 128] + sacc[t + 192]) + bias[t];
    hout[n * 64 + t] = fmaxf(v, 0.f);
  }
}

// ---------------- global mean pool (batch is sorted) ----------------
__global__ void pool_kernel(const float* __restrict__ h, const int* __restrict__ batch,
                            float* __restrict__ pool, float* __restrict__ pcnt, int n_nodes) {
  int c = threadIdx.x;  // 64 threads
  int n0 = blockIdx.x * 64;
  int n1 = min(n0 + 64, n_nodes);
  float acc = 0.f;
  int run = 0;
  int gcur = batch[n0];
  for (int n = n0; n < n1; ++n) {
    int g = batch[n];
    if (g != gcur) {
      atomicAdd(&pool[gcur * 64 + c], acc);
      if (c == 0) atomicAdd(&pcnt[gcur], (float)run);
      acc = 0.f; run = 0; gcur = g;
    }
    acc += h[n * 64 + c];
    ++run;
  }
  atomicAdd(&pool[gcur * 64 + c], acc);
  if (c == 0) atomicAdd(&pcnt[gcur], (float)run);
}

// ---------------- out = (pool/cnt) @ Wo + bo : [G,64]@[64,32] ----------------
__global__ void out_kernel(const float* __restrict__ pool, const float* __restrict__ pcnt,
                           const float* __restrict__ Wo, const float* __restrict__ bo,
                           float* __restrict__ out, int g_total) {
  int idx = blockIdx.x * blockDim.x + threadIdx.x;
  if (idx >= g_total * 32) return;
  int g = idx >> 5, d = idx & 31;
  float inv = 1.f / fmaxf(pcnt[g], 1.f);
  float acc = bo[d];
#pragma unroll
  for (int c = 0; c < 64; ++c) acc += (pool[g * 64 + c] * inv) * Wo[c * 32 + d];
  out[idx] = acc;
}

extern "C" void kernel_launch(void* const* d_in, const int* in_sizes, int n_in,
                              void* d_out, int out_size, void* d_ws, size_t ws_size,
                              hipStream_t stream) {
  const float* x     = (const float*)d_in[0];
  const int*   ei    = (const int*)d_in[1];
  const int*   batch = (const int*)d_in[2];
  const float* Wp    = (const float*)d_in[3];
  const float* bp    = (const float*)d_in[4];
  const float* Wo    = (const float*)d_in[5];
  const float* bo    = (const float*)d_in[6];
  const float* Wl[3]  = {(const float*)d_in[7],  (const float*)d_in[11], (const float*)d_in[15]};
  const float* Asl[3] = {(const float*)d_in[8],  (const float*)d_in[12], (const float*)d_in[16]};
  const float* Adl[3] = {(const float*)d_in[9],  (const float*)d_in[13], (const float*)d_in[17]};
  const float* Bl[3]  = {(const float*)d_in[10], (const float*)d_in[14], (const float*)d_in[18]};

  const int N = in_sizes[0] / 16;   // 50000
  const int E = in_sizes[1] / 2;    // 800000
  const int G = out_size / 32;      // 64
  const int Et = E + N;             // edges incl. self loops
  const int* src = ei;
  const int* dst = ei + E;

  // workspace carve (256B aligned)
  char* ws = (char*)d_ws;
  size_t off = 0;
  auto take = [&](size_t bytes) -> void* {
    void* p = ws + off;
    off = (off + bytes + 255) & ~(size_t)255;
    return p;
  };
  float* h_a   = (float*)take((size_t)N * 64 * 4);
  float* h_b   = (float*)take((size_t)N * 64 * 4);
  float* hw    = (float*)take((size_t)N * 256 * 4);
  float* alS   = (float*)take((size_t)N * 4 * 4);
  float* alD   = (float*)take((size_t)N * 4 * 4);
  int*   deg   = (int*)take((size_t)N * 4);
  int*   cnt   = (int*)take((size_t)N * 4);
  int*   rowp  = (int*)take((size_t)(N + 1) * 4);
  int*   col   = (int*)take((size_t)Et * 4);
  int*   row_of= (int*)take((size_t)Et * 4);
  float* ex    = (float*)take((size_t)Et * 4 * 4);
  float* Wa    = (float*)take((size_t)3 * 512 * 4);
  float* pool  = (float*)take((size_t)G * 64 * 4);
  float* pcnt  = (float*)take((size_t)G * 4);
  (void)ws_size; (void)n_in;

  // fold attention vectors into W (all 3 layers, one launch)
  prep_wa3<<<3, 256, 0, stream>>>(Wl[0], Asl[0], Adl[0], Wl[1], Asl[1], Adl[1],
                                  Wl[2], Asl[2], Adl[2], Wa);

  // CSR build
  init_deg_kernel<<<(N + 255) / 256, 256, 0, stream>>>(deg, N);
  hist_kernel<<<(E + 255) / 256, 256, 0, stream>>>(dst, deg, E);
  scan_kernel<<<1, 1024, 0, stream>>>(deg, rowp, N);
  init_csr_kernel<<<(N + 255) / 256, 256, 0, stream>>>(rowp, cnt, col, row_of, N);
  scatter_kernel<<<(E + 255) / 256, 256, 0, stream>>>(src, dst, rowp, cnt, col, row_of, E);

  // input projection
  proj_kernel<<<((size_t)N * 64 + 255) / 256, 256, 0, stream>>>(x, Wp, bp, h_a, N);

  // 3 GAT layers
  const float* hin = h_a;
  float* hout = h_b;
  for (int l = 0; l < 3; ++l) {
    hw_kernel<<<(N + HWROWS - 1) / HWROWS, 256, 0, stream>>>(hin, Wl[l], Wa + l * 512, hw, alS, alD, N);
    edge_ex_kernel<<<(Et + 255) / 256, 256, 0, stream>>>(col, row_of, alS, alD, ex, Et);
    gat_agg<<<N, 256, 0, stream>>>(rowp, col, ex, hw, Bl[l], hout, N);
    const float* tmp = hout;
    hout = (float*)hin;
    hin = tmp;
  }

  // pooling + output projection
  hipMemsetAsync(pool, 0, (size_t)G * 64 * 4, stream);
  hipMemsetAsync(pcnt, 0, (size_t)G * 4, stream);
  pool_kernel<<<(N + 63) / 64, 64, 0, stream>>>(hin, batch, pool, pcnt, N);
  out_kernel<<<(G * 32 + 255) / 256, 256, 0, stream>>>(pool, pcnt, Wo, bo, (float*)d_out, G);
}

// Round 5
// 658.373 us; speedup vs baseline: 1.5658x; 1.2312x over previous
//
#include <hip/hip_runtime.h>

#define NEG_SLOPE 0.2f

__device__ __forceinline__ float lrelu(float x) { return x > 0.f ? x : NEG_SLOPE * x; }

__device__ __forceinline__ float bf2f(unsigned short u) {
  return __uint_as_float(((unsigned int)u) << 16);
}
__device__ __forceinline__ unsigned short f2bf(float f) {
  unsigned int u = __float_as_uint(f);
  u += 0x7fffu + ((u >> 16) & 1u);   // round-to-nearest-even
  return (unsigned short)(u >> 16);
}

// ---------------- h0 = relu(x @ Wp + bp) : [N,16]@[16,64] ----------------
__global__ void proj_kernel(const float* __restrict__ x, const float* __restrict__ Wp,
                            const float* __restrict__ bp, float* __restrict__ h, int n_nodes) {
  int idx = blockIdx.x * blockDim.x + threadIdx.x;
  int n = idx >> 6, c = idx & 63;
  if (n >= n_nodes) return;
  float acc = bp[c];
#pragma unroll
  for (int k = 0; k < 16; ++k) acc += x[n * 16 + k] * Wp[k * 64 + c];
  h[n * 64 + c] = fmaxf(acc, 0.f);
}

// ---------------- CSR build (by destination), self-loop first ----------------
__global__ void init_deg_kernel(int* __restrict__ deg, int n) {
  int i = blockIdx.x * blockDim.x + threadIdx.x;
  if (i < n) deg[i] = 1;  // self loop
}

__global__ void hist_kernel(const int* __restrict__ dst, int* __restrict__ deg, int e) {
  int i = blockIdx.x * blockDim.x + threadIdx.x;
  if (i < e) atomicAdd(&deg[dst[i]], 1);
}

// single block of 1024 threads, n ~ 50k
__global__ void scan_kernel(const int* __restrict__ deg, int* __restrict__ rowp, int n) {
  __shared__ int sums[1024];
  int tid = threadIdx.x;
  int chunk = (n + 1023) >> 10;
  int start = tid * chunk;
  int end = min(start + chunk, n);
  int local = 0;
  for (int i = start; i < end; ++i) local += deg[i];
  sums[tid] = local;
  __syncthreads();
  for (int off = 1; off < 1024; off <<= 1) {
    int v = 0;
    if (tid >= off) v = sums[tid - off];
    __syncthreads();
    if (tid >= off) sums[tid] += v;
    __syncthreads();
  }
  int prefix = (tid == 0) ? 0 : sums[tid - 1];
  for (int i = start; i < end; ++i) {
    rowp[i] = prefix;
    prefix += deg[i];
  }
  if (tid == 1023) rowp[n] = sums[1023];
}

__global__ void init_csr_kernel(const int* __restrict__ rowp, int* __restrict__ cnt,
                                int* __restrict__ col, int* __restrict__ row_of, int n) {
  int i = blockIdx.x * blockDim.x + threadIdx.x;
  if (i < n) {
    cnt[i] = 1;           // slot 0 taken by self loop
    int p = rowp[i];
    col[p] = i;           // self loop src = i
    row_of[p] = i;
  }
}

__global__ void scatter_kernel(const int* __restrict__ src, const int* __restrict__ dst,
                               const int* __restrict__ rowp, int* __restrict__ cnt,
                               int* __restrict__ col, int* __restrict__ row_of, int e) {
  int i = blockIdx.x * blockDim.x + threadIdx.x;
  if (i < e) {
    int d = dst[i];
    int pos = rowp[d] + atomicAdd(&cnt[d], 1);
    col[pos] = src[i];
    row_of[pos] = d;
  }
}

// ---------------- fold a_src/a_dst into W: Wa[l][k][o] (o<4: src head o; o>=4: dst head o-4) ----
__global__ void prep_wa3(const float* __restrict__ W0, const float* __restrict__ as0, const float* __restrict__ ad0,
                         const float* __restrict__ W1, const float* __restrict__ as1, const float* __restrict__ ad1,
                         const float* __restrict__ W2, const float* __restrict__ as2, const float* __restrict__ ad2,
                         float* __restrict__ Wa) {
  int l = blockIdx.x;
  const float* W  = l == 0 ? W0  : l == 1 ? W1  : W2;
  const float* as = l == 0 ? as0 : l == 1 ? as1 : as2;
  const float* ad = l == 0 ? ad0 : l == 1 ? ad1 : ad2;
  int t = threadIdx.x;          // 256 threads
  int k = t >> 2, h = t & 3;
  float ss = 0.f, sd = 0.f;
  for (int c = 0; c < 64; ++c) {
    float w = W[k * 256 + h * 64 + c];
    ss += w * as[h * 64 + c];
    sd += w * ad[h * 64 + c];
  }
  Wa[l * 512 + k * 8 + h] = ss;
  Wa[l * 512 + k * 8 + 4 + h] = sd;
}

// ---------------- hw(bf16) = h @ W (64->256) + attention logits via folded Wa ----------------
#define HWROWS 64
__global__ __launch_bounds__(256) void hw_kernel(const float* __restrict__ h, const float* __restrict__ W,
                                                 const float* __restrict__ Wa,
                                                 unsigned short* __restrict__ hwb, float* __restrict__ al_s,
                                                 float* __restrict__ al_d, int n_nodes) {
  __shared__ float hs[HWROWS][68];   // +4 pad: conflict-free for both access patterns
  __shared__ float was[64][8];
  int t = threadIdx.x;
  int n0 = blockIdx.x * HWROWS;

  float wreg[64];
#pragma unroll
  for (int k = 0; k < 64; ++k) wreg[k] = W[k * 256 + t];
  for (int i = t; i < 512; i += 256) was[i >> 3][i & 7] = Wa[i];

  int rmax = min(HWROWS, n_nodes - n0);
  for (int i = t; i < HWROWS * 64; i += 256) {
    int r = i >> 6, c = i & 63;
    hs[r][c] = (r < rmax) ? h[(n0 + r) * 64 + c] : 0.f;
  }
  __syncthreads();

  for (int r = 0; r < rmax; ++r) {
    float acc = 0.f;
#pragma unroll
    for (int k4 = 0; k4 < 16; ++k4) {
      float4 hv = *(const float4*)&hs[r][4 * k4];
      acc += hv.x * wreg[4 * k4 + 0];
      acc += hv.y * wreg[4 * k4 + 1];
      acc += hv.z * wreg[4 * k4 + 2];
      acc += hv.w * wreg[4 * k4 + 3];
    }
    hwb[(size_t)(n0 + r) * 256 + t] = f2bf(acc);
  }

  // logits: 512 tasks (64 rows x 8 outputs), 2 per thread, 64-length LDS dots
#pragma unroll
  for (int j = 0; j < 2; ++j) {
    int task = t + j * 256;
    int r = task >> 3, o = task & 7;
    if (r < rmax) {
      float acc = 0.f;
#pragma unroll 8
      for (int k = 0; k < 64; ++k) acc += hs[r][k] * was[k][o];
      int n = n0 + r;
      if (o < 4) al_s[n * 4 + o] = acc;
      else       al_d[n * 4 + (o - 4)] = acc;
    }
  }
}

// ---------------- per-edge unnormalized attention weight (4 heads) ----------------
__global__ void edge_ex_kernel(const int* __restrict__ col, const int* __restrict__ row_of,
                               const float* __restrict__ alS, const float* __restrict__ alD,
                               float* __restrict__ ex, int ecnt) {
  int p = blockIdx.x * blockDim.x + threadIdx.x;
  if (p >= ecnt) return;
  int s = col[p], d = row_of[p];
  float4 as = *(const float4*)(alS + s * 4);
  float4 ad = *(const float4*)(alD + d * 4);
  float4 e;
  e.x = expf(lrelu(as.x + ad.x));
  e.y = expf(lrelu(as.y + ad.y));
  e.z = expf(lrelu(as.z + ad.z));
  e.w = expf(lrelu(as.w + ad.w));
  *(float4*)(ex + p * 4) = e;
}

// ---------------- single-pass aggregate, one wave per node ----------------
// lane holds channels 4*lane..4*lane+3 (head = lane>>4); per-head denom is
// lane-redundant (no reduction needed); head-mean via 2 shfl_xor at the end.
__global__ __launch_bounds__(256) void gat_agg(const int* __restrict__ rowp, const int* __restrict__ col,
                                               const float* __restrict__ ex,
                                               const unsigned short* __restrict__ hwb,
                                               const float* __restrict__ bias, float* __restrict__ hout,
                                               int n_nodes) {
  int lane = threadIdx.x & 63;
  int node = blockIdx.x * 4 + (threadIdx.x >> 6);
  if (node >= n_nodes) return;
  int base = rowp[node];
  int deg = rowp[node + 1] - base;
  int head = lane >> 4;

  float a0 = 0.f, a1 = 0.f, a2 = 0.f, a3 = 0.f, denom = 0.f;
#pragma unroll 4
  for (int i = 0; i < deg; ++i) {
    int s = col[base + i];                       // wave-uniform
    float w = ex[(base + i) * 4 + head];         // 16B line broadcast
    denom += w;
    ushort4 v = *(const ushort4*)(hwb + ((size_t)s << 8) + (lane << 2));  // 512B/wave
    a0 += w * bf2f(v.x);
    a1 += w * bf2f(v.y);
    a2 += w * bf2f(v.z);
    a3 += w * bf2f(v.w);
  }
  float inv = 1.f / denom;          // per-head softmax normalization
  a0 *= inv; a1 *= inv; a2 *= inv; a3 *= inv;

  // head mean: sum lanes {l, l^16, l^32, l^48} (same channel-within-head)
  a0 += __shfl_xor(a0, 16); a0 += __shfl_xor(a0, 32);
  a1 += __shfl_xor(a1, 16); a1 += __shfl_xor(a1, 32);
  a2 += __shfl_xor(a2, 16); a2 += __shfl_xor(a2, 32);
  a3 += __shfl_xor(a3, 16); a3 += __shfl_xor(a3, 32);

  if (lane < 16) {
    float4 b = *(const float4*)(bias + lane * 4);
    float4 o;
    o.x = fmaxf(0.25f * a0 + b.x, 0.f);
    o.y = fmaxf(0.25f * a1 + b.y, 0.f);
    o.z = fmaxf(0.25f * a2 + b.z, 0.f);
    o.w = fmaxf(0.25f * a3 + b.w, 0.f);
    *(float4*)(hout + (size_t)node * 64 + lane * 4) = o;
  }
}

// ---------------- global mean pool (batch is sorted) ----------------
__global__ void pool_kernel(const float* __restrict__ h, const int* __restrict__ batch,
                            float* __restrict__ pool, float* __restrict__ pcnt, int n_nodes) {
  int c = threadIdx.x;  // 64 threads
  int n0 = blockIdx.x * 64;
  int n1 = min(n0 + 64, n_nodes);
  float acc = 0.f;
  int run = 0;
  int gcur = batch[n0];
  for (int n = n0; n < n1; ++n) {
    int g = batch[n];
    if (g != gcur) {
      atomicAdd(&pool[gcur * 64 + c], acc);
      if (c == 0) atomicAdd(&pcnt[gcur], (float)run);
      acc = 0.f; run = 0; gcur = g;
    }
    acc += h[n * 64 + c];
    ++run;
  }
  atomicAdd(&pool[gcur * 64 + c], acc);
  if (c == 0) atomicAdd(&pcnt[gcur], (float)run);
}

// ---------------- out = (pool/cnt) @ Wo + bo : [G,64]@[64,32] ----------------
__global__ void out_kernel(const float* __restrict__ pool, const float* __restrict__ pcnt,
                           const float* __restrict__ Wo, const float* __restrict__ bo,
                           float* __restrict__ out, int g_total) {
  int idx = blockIdx.x * blockDim.x + threadIdx.x;
  if (idx >= g_total * 32) return;
  int g = idx >> 5, d = idx & 31;
  float inv = 1.f / fmaxf(pcnt[g], 1.f);
  float acc = bo[d];
#pragma unroll
  for (int c = 0; c < 64; ++c) acc += (pool[g * 64 + c] * inv) * Wo[c * 32 + d];
  out[idx] = acc;
}

extern "C" void kernel_launch(void* const* d_in, const int* in_sizes, int n_in,
                              void* d_out, int out_size, void* d_ws, size_t ws_size,
                              hipStream_t stream) {
  const float* x     = (const float*)d_in[0];
  const int*   ei    = (const int*)d_in[1];
  const int*   batch = (const int*)d_in[2];
  const float* Wp    = (const float*)d_in[3];
  const float* bp    = (const float*)d_in[4];
  const float* Wo    = (const float*)d_in[5];
  const float* bo    = (const float*)d_in[6];
  const float* Wl[3]  = {(const float*)d_in[7],  (const float*)d_in[11], (const float*)d_in[15]};
  const float* Asl[3] = {(const float*)d_in[8],  (const float*)d_in[12], (const float*)d_in[16]};
  const float* Adl[3] = {(const float*)d_in[9],  (const float*)d_in[13], (const float*)d_in[17]};
  const float* Bl[3]  = {(const float*)d_in[10], (const float*)d_in[14], (const float*)d_in[18]};

  const int N = in_sizes[0] / 16;   // 50000
  const int E = in_sizes[1] / 2;    // 800000
  const int G = out_size / 32;      // 64
  const int Et = E + N;             // edges incl. self loops
  const int* src = ei;
  const int* dst = ei + E;

  // workspace carve (256B aligned)
  char* ws = (char*)d_ws;
  size_t off = 0;
  auto take = [&](size_t bytes) -> void* {
    void* p = ws + off;
    off = (off + bytes + 255) & ~(size_t)255;
    return p;
  };
  float* h_a   = (float*)take((size_t)N * 64 * 4);
  float* h_b   = (float*)take((size_t)N * 64 * 4);
  unsigned short* hwb = (unsigned short*)take((size_t)N * 256 * 2);
  float* alS   = (float*)take((size_t)N * 4 * 4);
  float* alD   = (float*)take((size_t)N * 4 * 4);
  int*   deg   = (int*)take((size_t)N * 4);
  int*   cnt   = (int*)take((size_t)N * 4);
  int*   rowp  = (int*)take((size_t)(N + 1) * 4);
  int*   col   = (int*)take((size_t)Et * 4);
  int*   row_of= (int*)take((size_t)Et * 4);
  float* ex    = (float*)take((size_t)Et * 4 * 4);
  float* Wa    = (float*)take((size_t)3 * 512 * 4);
  float* pool  = (float*)take((size_t)G * 64 * 4);
  float* pcnt  = (float*)take((size_t)G * 4);
  (void)ws_size; (void)n_in;

  // fold attention vectors into W (all 3 layers, one launch)
  prep_wa3<<<3, 256, 0, stream>>>(Wl[0], Asl[0], Adl[0], Wl[1], Asl[1], Adl[1],
                                  Wl[2], Asl[2], Adl[2], Wa);

  // CSR build
  init_deg_kernel<<<(N + 255) / 256, 256, 0, stream>>>(deg, N);
  hist_kernel<<<(E + 255) / 256, 256, 0, stream>>>(dst, deg, E);
  scan_kernel<<<1, 1024, 0, stream>>>(deg, rowp, N);
  init_csr_kernel<<<(N + 255) / 256, 256, 0, stream>>>(rowp, cnt, col, row_of, N);
  scatter_kernel<<<(E + 255) / 256, 256, 0, stream>>>(src, dst, rowp, cnt, col, row_of, E);

  // input projection
  proj_kernel<<<((size_t)N * 64 + 255) / 256, 256, 0, stream>>>(x, Wp, bp, h_a, N);

  // 3 GAT layers
  const float* hin = h_a;
  float* hout = h_b;
  for (int l = 0; l < 3; ++l) {
    hw_kernel<<<(N + HWROWS - 1) / HWROWS, 256, 0, stream>>>(hin, Wl[l], Wa + l * 512, hwb, alS, alD, N);
    edge_ex_kernel<<<(Et + 255) / 256, 256, 0, stream>>>(col, row_of, alS, alD, ex, Et);
    gat_agg<<<(N + 3) / 4, 256, 0, stream>>>(rowp, col, ex, hwb, Bl[l], hout, N);
    const float* tmp = hout;
    hout = (float*)hin;
    hin = tmp;
  }

  // pooling + output projection
  hipMemsetAsync(pool, 0, (size_t)G * 64 * 4, stream);
  hipMemsetAsync(pcnt, 0, (size_t)G * 4, stream);
  pool_kernel<<<(N + 63) / 64, 64, 0, stream>>>(hin, batch, pool, pcnt, N);
  out_kernel<<<(G * 32 + 255) / 256, 256, 0, stream>>>(pool, pcnt, Wo, bo, (float*)d_out, G);
}

// Round 6
// 551.178 us; speedup vs baseline: 1.8703x; 1.1945x over previous
//
#include <hip/hip_runtime.h>

#define NEG_SLOPE 0.2f

typedef __attribute__((ext_vector_type(8))) short bf16x8;
typedef __attribute__((ext_vector_type(4))) float f32x4;

__device__ __forceinline__ float lrelu(float x) { return x > 0.f ? x : NEG_SLOPE * x; }

__device__ __forceinline__ float bf2f(unsigned short u) {
  return __uint_as_float(((unsigned int)u) << 16);
}
__device__ __forceinline__ unsigned short f2bf(float f) {
  unsigned int u = __float_as_uint(f);
  u += 0x7fffu + ((u >> 16) & 1u);   // round-to-nearest-even
  return (unsigned short)(u >> 16);
}

// ---------------- h0 = relu(x @ Wp + bp) : [N,16]@[16,64], bf16 out ----------------
__global__ void proj_kernel(const float* __restrict__ x, const float* __restrict__ Wp,
                            const float* __restrict__ bp, unsigned short* __restrict__ h,
                            int n_nodes) {
  int idx = blockIdx.x * blockDim.x + threadIdx.x;
  int n = idx >> 6, c = idx & 63;
  if (n >= n_nodes) return;
  float acc = bp[c];
#pragma unroll
  for (int k = 0; k < 16; ++k) acc += x[n * 16 + k] * Wp[k * 64 + c];
  h[n * 64 + c] = f2bf(fmaxf(acc, 0.f));
}

// ---------------- CSR build (by destination), self-loop first ----------------
__global__ void init_deg_kernel(int* __restrict__ deg, int n) {
  int i = blockIdx.x * blockDim.x + threadIdx.x;
  if (i < n) deg[i] = 1;  // self loop
}

__global__ void hist_kernel(const int* __restrict__ dst, int* __restrict__ deg, int e) {
  int i = blockIdx.x * blockDim.x + threadIdx.x;
  if (i < e) atomicAdd(&deg[dst[i]], 1);
}

// single block of 1024 threads, n ~ 50k
__global__ void scan_kernel(const int* __restrict__ deg, int* __restrict__ rowp, int n) {
  __shared__ int sums[1024];
  int tid = threadIdx.x;
  int chunk = (n + 1023) >> 10;
  int start = tid * chunk;
  int end = min(start + chunk, n);
  int local = 0;
  for (int i = start; i < end; ++i) local += deg[i];
  sums[tid] = local;
  __syncthreads();
  for (int off = 1; off < 1024; off <<= 1) {
    int v = 0;
    if (tid >= off) v = sums[tid - off];
    __syncthreads();
    if (tid >= off) sums[tid] += v;
    __syncthreads();
  }
  int prefix = (tid == 0) ? 0 : sums[tid - 1];
  for (int i = start; i < end; ++i) {
    rowp[i] = prefix;
    prefix += deg[i];
  }
  if (tid == 1023) rowp[n] = sums[1023];
}

__global__ void init_csr_kernel(const int* __restrict__ rowp, int* __restrict__ cnt,
                                int* __restrict__ col, int* __restrict__ row_of, int n) {
  int i = blockIdx.x * blockDim.x + threadIdx.x;
  if (i < n) {
    cnt[i] = 1;           // slot 0 taken by self loop
    int p = rowp[i];
    col[p] = i;           // self loop src = i
    row_of[p] = i;
  }
}

__global__ void scatter_kernel(const int* __restrict__ src, const int* __restrict__ dst,
                               const int* __restrict__ rowp, int* __restrict__ cnt,
                               int* __restrict__ col, int* __restrict__ row_of, int e) {
  int i = blockIdx.x * blockDim.x + threadIdx.x;
  if (i < e) {
    int d = dst[i];
    int pos = rowp[d] + atomicAdd(&cnt[d], 1);
    col[pos] = src[i];
    row_of[pos] = d;
  }
}

// ---------------- fold a_src/a_dst into W: Wa[l][k][o] (o<4: src head o; o>=4: dst head o-4) ----
__global__ void prep_wa3(const float* __restrict__ W0, const float* __restrict__ as0, const float* __restrict__ ad0,
                         const float* __restrict__ W1, const float* __restrict__ as1, const float* __restrict__ ad1,
                         const float* __restrict__ W2, const float* __restrict__ as2, const float* __restrict__ ad2,
                         float* __restrict__ Wa) {
  int l = blockIdx.x;
  const float* W  = l == 0 ? W0  : l == 1 ? W1  : W2;
  const float* as = l == 0 ? as0 : l == 1 ? as1 : as2;
  const float* ad = l == 0 ? ad0 : l == 1 ? ad1 : ad2;
  int t = threadIdx.x;          // 256 threads
  int k = t >> 2, h = t & 3;
  float ss = 0.f, sd = 0.f;
  for (int c = 0; c < 64; ++c) {
    float w = W[k * 256 + h * 64 + c];
    ss += w * as[h * 64 + c];
    sd += w * ad[h * 64 + c];
  }
  Wa[l * 512 + k * 8 + h] = ss;
  Wa[l * 512 + k * 8 + 4 + h] = sd;
}

// ---------------- pre-swizzle W (and Wa) into MFMA B-fragment order, bf16 ----------------
// B-frag for mfma_f32_16x16x32_bf16: lane holds B[k = kk*32 + (lane>>4)*8 + j][col = nt*16 + (lane&15)]
// Wsw layout: [layer][nt*128 + kk*64 + lane][8]  (nt=0..15, kk=0..1)
// Wasw layout: [layer][kk*64 + lane][8]  (cols 0..7 valid, 8..15 zero)
__global__ void prep_wsw(const float* __restrict__ W0, const float* __restrict__ W1,
                         const float* __restrict__ W2, const float* __restrict__ Wa,
                         unsigned short* __restrict__ Wsw, unsigned short* __restrict__ Wasw) {
  int l = blockIdx.x;
  const float* W = l == 0 ? W0 : l == 1 ? W1 : W2;
  int t = threadIdx.x;  // 256
  for (int s = t; s < 2048; s += 256) {
    int nt = s >> 7, kk = (s >> 6) & 1, lane = s & 63;
    int kq = lane >> 4, r = lane & 15;
#pragma unroll
    for (int j = 0; j < 8; ++j) {
      int k = kk * 32 + kq * 8 + j;
      Wsw[(size_t)l * 16384 + (size_t)s * 8 + j] = f2bf(W[k * 256 + nt * 16 + r]);
    }
  }
  if (t < 128) {
    int lane = t & 63, kq = lane >> 4, r = lane & 15;
    int kk = t >> 6;
#pragma unroll
    for (int j = 0; j < 8; ++j) {
      int k = kk * 32 + kq * 8 + j;
      float v = (r < 8) ? Wa[l * 512 + k * 8 + r] : 0.f;
      Wasw[l * 1024 + t * 8 + j] = f2bf(v);
    }
  }
}

// ---------------- hw(bf16) = h @ W via MFMA + attention logits ----------------
// block = 256 threads = 4 waves; 64 rows x 256 cols per block; wave w owns cols w*64..w*64+63.
__global__ __launch_bounds__(256) void hw_kernel(const unsigned short* __restrict__ hb,
                                                 const unsigned short* __restrict__ Wsw,
                                                 const unsigned short* __restrict__ Wasw,
                                                 unsigned short* __restrict__ hwb,
                                                 float* __restrict__ al_s, float* __restrict__ al_d,
                                                 int n_nodes) {
  int t = threadIdx.x;
  int w = t >> 6, lane = t & 63;
  int kq = lane >> 4, r16 = lane & 15;
  int n0 = blockIdx.x << 6;

  // A fragments: 4 m-tiles x 2 k-steps; direct 16B loads from row-major bf16 h
  bf16x8 a[4][2];
#pragma unroll
  for (int m = 0; m < 4; ++m) {
    int row = min(n0 + m * 16 + r16, n_nodes - 1);
    const unsigned short* p = hb + (size_t)row * 64 + kq * 8;
    a[m][0] = *(const bf16x8*)(p);
    a[m][1] = *(const bf16x8*)(p + 32);
  }
  // B fragments: 4 local n-tiles x 2 k-steps
  bf16x8 b[4][2];
#pragma unroll
  for (int nt = 0; nt < 4; ++nt) {
    int ntg = w * 4 + nt;
    const unsigned short* p = Wsw + ((size_t)ntg * 128 + lane) * 8;
    b[nt][0] = *(const bf16x8*)(p);
    b[nt][1] = *(const bf16x8*)(p + 512);
  }

  f32x4 acc[4][4];
#pragma unroll
  for (int m = 0; m < 4; ++m)
#pragma unroll
    for (int nt = 0; nt < 4; ++nt) acc[m][nt] = (f32x4){0.f, 0.f, 0.f, 0.f};

#pragma unroll
  for (int m = 0; m < 4; ++m)
#pragma unroll
    for (int nt = 0; nt < 4; ++nt) {
      acc[m][nt] = __builtin_amdgcn_mfma_f32_16x16x32_bf16(a[m][0], b[nt][0], acc[m][nt], 0, 0, 0);
      acc[m][nt] = __builtin_amdgcn_mfma_f32_16x16x32_bf16(a[m][1], b[nt][1], acc[m][nt], 0, 0, 0);
    }

  // store hw as bf16: C/D mapping col=lane&15, row=(lane>>4)*4+reg
#pragma unroll
  for (int m = 0; m < 4; ++m) {
#pragma unroll
    for (int j = 0; j < 4; ++j) {
      int row = n0 + m * 16 + kq * 4 + j;
      if (row < n_nodes) {
#pragma unroll
        for (int nt = 0; nt < 4; ++nt) {
          int col = (w * 4 + nt) * 16 + r16;
          hwb[(size_t)row * 256 + col] = f2bf(acc[m][nt][j]);
        }
      }
    }
  }

  // attention logits: wave w handles m-tile w; B = folded Wa (8 valid cols)
  bf16x8 ba0 = *(const bf16x8*)(Wasw + lane * 8);
  bf16x8 ba1 = *(const bf16x8*)(Wasw + (64 + lane) * 8);
  f32x4 accl = (f32x4){0.f, 0.f, 0.f, 0.f};
  accl = __builtin_amdgcn_mfma_f32_16x16x32_bf16(a[w][0], ba0, accl, 0, 0, 0);
  accl = __builtin_amdgcn_mfma_f32_16x16x32_bf16(a[w][1], ba1, accl, 0, 0, 0);
  if (r16 < 8) {
#pragma unroll
    for (int j = 0; j < 4; ++j) {
      int row = n0 + w * 16 + kq * 4 + j;
      if (row < n_nodes) {
        if (r16 < 4) al_s[row * 4 + r16] = accl[j];
        else         al_d[row * 4 + (r16 - 4)] = accl[j];
      }
    }
  }
}

// ---------------- per-edge unnormalized attention weight (4 heads) ----------------
__global__ void edge_ex_kernel(const int* __restrict__ col, const int* __restrict__ row_of,
                               const float* __restrict__ alS, const float* __restrict__ alD,
                               float* __restrict__ ex, int ecnt) {
  int p = blockIdx.x * blockDim.x + threadIdx.x;
  if (p >= ecnt) return;
  int s = col[p], d = row_of[p];
  float4 as = *(const float4*)(alS + s * 4);
  float4 ad = *(const float4*)(alD + d * 4);
  float4 e;
  e.x = expf(lrelu(as.x + ad.x));
  e.y = expf(lrelu(as.y + ad.y));
  e.z = expf(lrelu(as.z + ad.z));
  e.w = expf(lrelu(as.w + ad.w));
  *(float4*)(ex + p * 4) = e;
}

// ---------------- single-pass aggregate, one wave per node ----------------
__global__ __launch_bounds__(256) void gat_agg(const int* __restrict__ rowp, const int* __restrict__ col,
                                               const float* __restrict__ ex,
                                               const unsigned short* __restrict__ hwb,
                                               const float* __restrict__ bias,
                                               unsigned short* __restrict__ hout,
                                               int n_nodes) {
  int lane = threadIdx.x & 63;
  int node = blockIdx.x * 4 + (threadIdx.x >> 6);
  if (node >= n_nodes) return;
  int base = __builtin_amdgcn_readfirstlane(rowp[node]);
  int deg  = __builtin_amdgcn_readfirstlane(rowp[node + 1]) - base;
  int head = lane >> 4;

  float a0 = 0.f, a1 = 0.f, a2 = 0.f, a3 = 0.f, denom = 0.f;
#pragma unroll 4
  for (int i = 0; i < deg; ++i) {
    int s = __builtin_amdgcn_readfirstlane(col[base + i]);   // wave-uniform -> SGPR
    float w = ex[(base + i) * 4 + head];                     // 16B line broadcast
    denom += w;
    ushort4 v = *(const ushort4*)(hwb + ((size_t)s << 8) + (lane << 2));  // 512B/wave
    a0 += w * bf2f(v.x);
    a1 += w * bf2f(v.y);
    a2 += w * bf2f(v.z);
    a3 += w * bf2f(v.w);
  }
  float inv = 1.f / denom;          // per-head softmax normalization
  a0 *= inv; a1 *= inv; a2 *= inv; a3 *= inv;

  // head mean: sum lanes {l, l^16, l^32, l^48} (same channel-within-head)
  a0 += __shfl_xor(a0, 16); a0 += __shfl_xor(a0, 32);
  a1 += __shfl_xor(a1, 16); a1 += __shfl_xor(a1, 32);
  a2 += __shfl_xor(a2, 16); a2 += __shfl_xor(a2, 32);
  a3 += __shfl_xor(a3, 16); a3 += __shfl_xor(a3, 32);

  if (lane < 16) {
    float4 b = *(const float4*)(bias + lane * 4);
    ushort4 o;
    o.x = f2bf(fmaxf(0.25f * a0 + b.x, 0.f));
    o.y = f2bf(fmaxf(0.25f * a1 + b.y, 0.f));
    o.z = f2bf(fmaxf(0.25f * a2 + b.z, 0.f));
    o.w = f2bf(fmaxf(0.25f * a3 + b.w, 0.f));
    *(ushort4*)(hout + (size_t)node * 64 + lane * 4) = o;
  }
}

// ---------------- global mean pool (batch is sorted), bf16 in ----------------
__global__ void pool_kernel(const unsigned short* __restrict__ h, const int* __restrict__ batch,
                            float* __restrict__ pool, float* __restrict__ pcnt, int n_nodes) {
  int c = threadIdx.x;  // 64 threads
  int n0 = blockIdx.x * 64;
  int n1 = min(n0 + 64, n_nodes);
  float acc = 0.f;
  int run = 0;
  int gcur = batch[n0];
  for (int n = n0; n < n1; ++n) {
    int g = batch[n];
    if (g != gcur) {
      atomicAdd(&pool[gcur * 64 + c], acc);
      if (c == 0) atomicAdd(&pcnt[gcur], (float)run);
      acc = 0.f; run = 0; gcur = g;
    }
    acc += bf2f(h[(size_t)n * 64 + c]);
    ++run;
  }
  atomicAdd(&pool[gcur * 64 + c], acc);
  if (c == 0) atomicAdd(&pcnt[gcur], (float)run);
}

// ---------------- out = (pool/cnt) @ Wo + bo : [G,64]@[64,32] ----------------
__global__ void out_kernel(const float* __restrict__ pool, const float* __restrict__ pcnt,
                           const float* __restrict__ Wo, const float* __restrict__ bo,
                           float* __restrict__ out, int g_total) {
  int idx = blockIdx.x * blockDim.x + threadIdx.x;
  if (idx >= g_total * 32) return;
  int g = idx >> 5, d = idx & 31;
  float inv = 1.f / fmaxf(pcnt[g], 1.f);
  float acc = bo[d];
#pragma unroll
  for (int c = 0; c < 64; ++c) acc += (pool[g * 64 + c] * inv) * Wo[c * 32 + d];
  out[idx] = acc;
}

extern "C" void kernel_launch(void* const* d_in, const int* in_sizes, int n_in,
                              void* d_out, int out_size, void* d_ws, size_t ws_size,
                              hipStream_t stream) {
  const float* x     = (const float*)d_in[0];
  const int*   ei    = (const int*)d_in[1];
  const int*   batch = (const int*)d_in[2];
  const float* Wp    = (const float*)d_in[3];
  const float* bp    = (const float*)d_in[4];
  const float* Wo    = (const float*)d_in[5];
  const float* bo    = (const float*)d_in[6];
  const float* Wl[3]  = {(const float*)d_in[7],  (const float*)d_in[11], (const float*)d_in[15]};
  const float* Asl[3] = {(const float*)d_in[8],  (const float*)d_in[12], (const float*)d_in[16]};
  const float* Adl[3] = {(const float*)d_in[9],  (const float*)d_in[13], (const float*)d_in[17]};
  const float* Bl[3]  = {(const float*)d_in[10], (const float*)d_in[14], (const float*)d_in[18]};

  const int N = in_sizes[0] / 16;   // 50000
  const int E = in_sizes[1] / 2;    // 800000
  const int G = out_size / 32;      // 64
  const int Et = E + N;             // edges incl. self loops
  const int* src = ei;
  const int* dst = ei + E;

  // workspace carve (256B aligned)
  char* ws = (char*)d_ws;
  size_t off = 0;
  auto take = [&](size_t bytes) -> void* {
    void* p = ws + off;
    off = (off + bytes + 255) & ~(size_t)255;
    return p;
  };
  unsigned short* h_a = (unsigned short*)take((size_t)N * 64 * 2);
  unsigned short* h_b = (unsigned short*)take((size_t)N * 64 * 2);
  unsigned short* hwb = (unsigned short*)take((size_t)N * 256 * 2);
  float* alS   = (float*)take((size_t)N * 4 * 4);
  float* alD   = (float*)take((size_t)N * 4 * 4);
  int*   deg   = (int*)take((size_t)N * 4);
  int*   cnt   = (int*)take((size_t)N * 4);
  int*   rowp  = (int*)take((size_t)(N + 1) * 4);
  int*   col   = (int*)take((size_t)Et * 4);
  int*   row_of= (int*)take((size_t)Et * 4);
  float* ex    = (float*)take((size_t)Et * 4 * 4);
  float* Wa    = (float*)take((size_t)3 * 512 * 4);
  unsigned short* Wsw  = (unsigned short*)take((size_t)3 * 16384 * 2);
  unsigned short* Wasw = (unsigned short*)take((size_t)3 * 1024 * 2);
  float* pool  = (float*)take((size_t)G * 64 * 4);
  float* pcnt  = (float*)take((size_t)G * 4);
  (void)ws_size; (void)n_in;

  // fold attention vectors into W, then pre-swizzle to MFMA B-fragment order
  prep_wa3<<<3, 256, 0, stream>>>(Wl[0], Asl[0], Adl[0], Wl[1], Asl[1], Adl[1],
                                  Wl[2], Asl[2], Adl[2], Wa);
  prep_wsw<<<3, 256, 0, stream>>>(Wl[0], Wl[1], Wl[2], Wa, Wsw, Wasw);

  // CSR build
  init_deg_kernel<<<(N + 255) / 256, 256, 0, stream>>>(deg, N);
  hist_kernel<<<(E + 255) / 256, 256, 0, stream>>>(dst, deg, E);
  scan_kernel<<<1, 1024, 0, stream>>>(deg, rowp, N);
  init_csr_kernel<<<(N + 255) / 256, 256, 0, stream>>>(rowp, cnt, col, row_of, N);
  scatter_kernel<<<(E + 255) / 256, 256, 0, stream>>>(src, dst, rowp, cnt, col, row_of, E);

  // input projection
  proj_kernel<<<((size_t)N * 64 + 255) / 256, 256, 0, stream>>>(x, Wp, bp, h_a, N);

  // 3 GAT layers
  const unsigned short* hin = h_a;
  unsigned short* hout = h_b;
  for (int l = 0; l < 3; ++l) {
    hw_kernel<<<(N + 63) / 64, 256, 0, stream>>>(hin, Wsw + (size_t)l * 16384,
                                                 Wasw + (size_t)l * 1024, hwb, alS, alD, N);
    edge_ex_kernel<<<(Et + 255) / 256, 256, 0, stream>>>(col, row_of, alS, alD, ex, Et);
    gat_agg<<<(N + 3) / 4, 256, 0, stream>>>(rowp, col, ex, hwb, Bl[l], hout, N);
    const unsigned short* tmp = hout;
    hout = (unsigned short*)hin;
    hin = tmp;
  }

  // pooling + output projection
  hipMemsetAsync(pool, 0, (size_t)G * 64 * 4, stream);
  hipMemsetAsync(pcnt, 0, (size_t)G * 4, stream);
  pool_kernel<<<(N + 63) / 64, 64, 0, stream>>>(hin, batch, pool, pcnt, N);
  out_kernel<<<(G * 32 + 255) / 256, 256, 0, stream>>>(pool, pcnt, Wo, bo, (float*)d_out, G);
}

// Round 7
// 443.640 us; speedup vs baseline: 2.3237x; 1.2424x over previous
//
#include <hip/hip_runtime.h>

#define NEG_SLOPE 0.2f

typedef __attribute__((ext_vector_type(8))) short bf16x8;
typedef __attribute__((ext_vector_type(4))) float f32x4;

__device__ __forceinline__ float lrelu(float x) { return x > 0.f ? x : NEG_SLOPE * x; }

__device__ __forceinline__ float bf2f(unsigned short u) {
  return __uint_as_float(((unsigned int)u) << 16);
}
__device__ __forceinline__ unsigned short f2bf(float f) {
  unsigned int u = __float_as_uint(f);
  u += 0x7fffu + ((u >> 16) & 1u);   // round-to-nearest-even
  return (unsigned short)(u >> 16);
}

// ---------------- h0 = relu(x @ Wp + bp) : [N,16]@[16,64], bf16 out ----------------
__global__ void proj_kernel(const float* __restrict__ x, const float* __restrict__ Wp,
                            const float* __restrict__ bp, unsigned short* __restrict__ h,
                            int n_nodes) {
  int idx = blockIdx.x * blockDim.x + threadIdx.x;
  int n = idx >> 6, c = idx & 63;
  if (n >= n_nodes) return;
  float acc = bp[c];
#pragma unroll
  for (int k = 0; k < 16; ++k) acc += x[n * 16 + k] * Wp[k * 64 + c];
  h[n * 64 + c] = f2bf(fmaxf(acc, 0.f));
}

// ---------------- CSR build (by destination), self-loop first ----------------
__global__ void hist_kernel(const int* __restrict__ dst, int* __restrict__ deg, int e) {
  int i = blockIdx.x * blockDim.x + threadIdx.x;
  if (i < e) atomicAdd(&deg[dst[i]], 1);
}

// phase A: per-block (1024 elems) local exclusive scan of (deg[i]+1); block sums out.
__global__ __launch_bounds__(256) void scan_a(const int* __restrict__ deg, int* __restrict__ rowp,
                                              int* __restrict__ bsum, int n) {
  __shared__ int s[256];
  int t = threadIdx.x;
  int base = blockIdx.x * 1024 + t * 4;
  int d0 = (base + 0 < n) ? deg[base + 0] + 1 : 0;
  int d1 = (base + 1 < n) ? deg[base + 1] + 1 : 0;
  int d2 = (base + 2 < n) ? deg[base + 2] + 1 : 0;
  int d3 = (base + 3 < n) ? deg[base + 3] + 1 : 0;
  s[t] = d0 + d1 + d2 + d3;
  __syncthreads();
  for (int off = 1; off < 256; off <<= 1) {
    int v = 0;
    if (t >= off) v = s[t - off];
    __syncthreads();
    if (t >= off) s[t] += v;
    __syncthreads();
  }
  int p = (t == 0) ? 0 : s[t - 1];
  if (base + 0 < n) rowp[base + 0] = p;
  p += d0;
  if (base + 1 < n) rowp[base + 1] = p;
  p += d1;
  if (base + 2 < n) rowp[base + 2] = p;
  p += d2;
  if (base + 3 < n) rowp[base + 3] = p;
  if (t == 255) bsum[blockIdx.x] = s[255];
}

// phase B: single wave exclusive-scans <=64 block sums; bpre[64] = grand total.
__global__ void scan_b(const int* __restrict__ bsum, int* __restrict__ bpre, int nb) {
  int t = threadIdx.x;  // 64 threads = 1 wave
  int v = (t < nb) ? bsum[t] : 0;
  int orig = v;
#pragma unroll
  for (int off = 1; off < 64; off <<= 1) {
    int u = __shfl_up(v, off);
    if (t >= off) v += u;
  }
  bpre[t] = v - orig;
  if (t == 63) bpre[64] = v;
}

// phase C: add block prefixes; fused init_csr (self-loop slot 0).
__global__ void scan_c(int* __restrict__ rowp, const int* __restrict__ bpre,
                       int* __restrict__ cnt, int* __restrict__ col, int n) {
  int i = blockIdx.x * blockDim.x + threadIdx.x;
  if (i < n) {
    int r = rowp[i] + bpre[i >> 10];
    rowp[i] = r;
    cnt[i] = 1;       // slot 0 = self loop
    col[r] = i;
  }
  if (i == 0) rowp[n] = bpre[64];
}

__global__ void scatter_kernel(const int* __restrict__ src, const int* __restrict__ dst,
                               const int* __restrict__ rowp, int* __restrict__ cnt,
                               int* __restrict__ col, int e) {
  int i = blockIdx.x * blockDim.x + threadIdx.x;
  if (i < e) {
    int d = dst[i];
    int pos = rowp[d] + atomicAdd(&cnt[d], 1);
    col[pos] = src[i];
  }
}

// ---------------- fold a_src/a_dst into W: Wa[l][k][o] (o<4: src head o; o>=4: dst head o-4) ----
__global__ void prep_wa3(const float* __restrict__ W0, const float* __restrict__ as0, const float* __restrict__ ad0,
                         const float* __restrict__ W1, const float* __restrict__ as1, const float* __restrict__ ad1,
                         const float* __restrict__ W2, const float* __restrict__ as2, const float* __restrict__ ad2,
                         float* __restrict__ Wa) {
  int l = blockIdx.x;
  const float* W  = l == 0 ? W0  : l == 1 ? W1  : W2;
  const float* as = l == 0 ? as0 : l == 1 ? as1 : as2;
  const float* ad = l == 0 ? ad0 : l == 1 ? ad1 : ad2;
  int t = threadIdx.x;          // 256 threads
  int k = t >> 2, h = t & 3;
  float ss = 0.f, sd = 0.f;
  for (int c = 0; c < 64; ++c) {
    float w = W[k * 256 + h * 64 + c];
    ss += w * as[h * 64 + c];
    sd += w * ad[h * 64 + c];
  }
  Wa[l * 512 + k * 8 + h] = ss;
  Wa[l * 512 + k * 8 + 4 + h] = sd;
}

// ---------------- pre-swizzle W (and Wa) into MFMA B-fragment order, bf16 ----------------
// B-frag for mfma_f32_16x16x32_bf16: lane holds B[k = kk*32 + (lane>>4)*8 + j][col = nt*16 + (lane&15)]
// Wsw layout: [layer][nt*128 + kk*64 + lane][8]  (nt=0..15, kk=0..1)
// Wasw layout: [layer][kk*64 + lane][8]  (cols 0..7 valid, 8..15 zero)
__global__ void prep_wsw(const float* __restrict__ W0, const float* __restrict__ W1,
                         const float* __restrict__ W2, const float* __restrict__ Wa,
                         unsigned short* __restrict__ Wsw, unsigned short* __restrict__ Wasw) {
  int l = blockIdx.x;
  const float* W = l == 0 ? W0 : l == 1 ? W1 : W2;
  int t = threadIdx.x;  // 256
  for (int s = t; s < 2048; s += 256) {
    int nt = s >> 7, kk = (s >> 6) & 1, lane = s & 63;
    int kq = lane >> 4, r = lane & 15;
#pragma unroll
    for (int j = 0; j < 8; ++j) {
      int k = kk * 32 + kq * 8 + j;
      Wsw[(size_t)l * 16384 + (size_t)s * 8 + j] = f2bf(W[k * 256 + nt * 16 + r]);
    }
  }
  if (t < 128) {
    int lane = t & 63, kq = lane >> 4, r = lane & 15;
    int kk = t >> 6;
#pragma unroll
    for (int j = 0; j < 8; ++j) {
      int k = kk * 32 + kq * 8 + j;
      float v = (r < 8) ? Wa[l * 512 + k * 8 + r] : 0.f;
      Wasw[l * 1024 + t * 8 + j] = f2bf(v);
    }
  }
}

// ---------------- hw(bf16) = h @ W via MFMA + attention logits ----------------
// block = 256 threads = 4 waves; 64 rows x 256 cols per block; wave w owns cols w*64..w*64+63.
__global__ __launch_bounds__(256) void hw_kernel(const unsigned short* __restrict__ hb,
                                                 const unsigned short* __restrict__ Wsw,
                                                 const unsigned short* __restrict__ Wasw,
                                                 unsigned short* __restrict__ hwb,
                                                 float* __restrict__ al_s, float* __restrict__ al_d,
                                                 int n_nodes) {
  int t = threadIdx.x;
  int w = t >> 6, lane = t & 63;
  int kq = lane >> 4, r16 = lane & 15;
  int n0 = blockIdx.x << 6;

  // A fragments: 4 m-tiles x 2 k-steps; direct 16B loads from row-major bf16 h
  bf16x8 a[4][2];
#pragma unroll
  for (int m = 0; m < 4; ++m) {
    int row = min(n0 + m * 16 + r16, n_nodes - 1);
    const unsigned short* p = hb + (size_t)row * 64 + kq * 8;
    a[m][0] = *(const bf16x8*)(p);
    a[m][1] = *(const bf16x8*)(p + 32);
  }
  // B fragments: 4 local n-tiles x 2 k-steps
  bf16x8 b[4][2];
#pragma unroll
  for (int nt = 0; nt < 4; ++nt) {
    int ntg = w * 4 + nt;
    const unsigned short* p = Wsw + ((size_t)ntg * 128 + lane) * 8;
    b[nt][0] = *(const bf16x8*)(p);
    b[nt][1] = *(const bf16x8*)(p + 512);
  }

  f32x4 acc[4][4];
#pragma unroll
  for (int m = 0; m < 4; ++m)
#pragma unroll
    for (int nt = 0; nt < 4; ++nt) acc[m][nt] = (f32x4){0.f, 0.f, 0.f, 0.f};

#pragma unroll
  for (int m = 0; m < 4; ++m)
#pragma unroll
    for (int nt = 0; nt < 4; ++nt) {
      acc[m][nt] = __builtin_amdgcn_mfma_f32_16x16x32_bf16(a[m][0], b[nt][0], acc[m][nt], 0, 0, 0);
      acc[m][nt] = __builtin_amdgcn_mfma_f32_16x16x32_bf16(a[m][1], b[nt][1], acc[m][nt], 0, 0, 0);
    }

  // store hw as bf16: C/D mapping col=lane&15, row=(lane>>4)*4+reg
#pragma unroll
  for (int m = 0; m < 4; ++m) {
#pragma unroll
    for (int j = 0; j < 4; ++j) {
      int row = n0 + m * 16 + kq * 4 + j;
      if (row < n_nodes) {
#pragma unroll
        for (int nt = 0; nt < 4; ++nt) {
          int col = (w * 4 + nt) * 16 + r16;
          hwb[(size_t)row * 256 + col] = f2bf(acc[m][nt][j]);
        }
      }
    }
  }

  // attention logits: wave w handles m-tile w; B = folded Wa (8 valid cols)
  bf16x8 ba0 = *(const bf16x8*)(Wasw + lane * 8);
  bf16x8 ba1 = *(const bf16x8*)(Wasw + (64 + lane) * 8);
  f32x4 accl = (f32x4){0.f, 0.f, 0.f, 0.f};
  accl = __builtin_amdgcn_mfma_f32_16x16x32_bf16(a[w][0], ba0, accl, 0, 0, 0);
  accl = __builtin_amdgcn_mfma_f32_16x16x32_bf16(a[w][1], ba1, accl, 0, 0, 0);
  if (r16 < 8) {
#pragma unroll
    for (int j = 0; j < 4; ++j) {
      int row = n0 + w * 16 + kq * 4 + j;
      if (row < n_nodes) {
        if (r16 < 4) al_s[row * 4 + r16] = accl[j];
        else         al_d[row * 4 + (r16 - 4)] = accl[j];
      }
    }
  }
}

// ---------------- single-pass aggregate, one wave per node; exp fused (1 v_exp/edge/wave) ----
__global__ __launch_bounds__(256) void gat_agg(const int* __restrict__ rowp, const int* __restrict__ col,
                                               const float* __restrict__ alS, const float* __restrict__ alD,
                                               const unsigned short* __restrict__ hwb,
                                               const float* __restrict__ bias,
                                               unsigned short* __restrict__ hout,
                                               int n_nodes) {
  int lane = threadIdx.x & 63;
  int node = blockIdx.x * 4 + (threadIdx.x >> 6);
  if (node >= n_nodes) return;
  int base = __builtin_amdgcn_readfirstlane(rowp[node]);
  int deg  = __builtin_amdgcn_readfirstlane(rowp[node + 1]) - base;
  int head = lane >> 4;
  float ald = alD[node * 4 + head];

  float a0 = 0.f, a1 = 0.f, a2 = 0.f, a3 = 0.f, denom = 0.f;
#pragma unroll 4
  for (int i = 0; i < deg; ++i) {
    int s = __builtin_amdgcn_readfirstlane(col[base + i]);   // wave-uniform -> SGPR
    float w = __expf(lrelu(alS[s * 4 + head] + ald));        // one v_exp per edge per wave
    denom += w;
    ushort4 v = *(const ushort4*)(hwb + ((size_t)s << 8) + (lane << 2));  // 512B/wave
    a0 += w * bf2f(v.x);
    a1 += w * bf2f(v.y);
    a2 += w * bf2f(v.z);
    a3 += w * bf2f(v.w);
  }
  float inv = 1.f / denom;          // per-head softmax normalization
  a0 *= inv; a1 *= inv; a2 *= inv; a3 *= inv;

  // head mean: sum lanes {l, l^16, l^32, l^48} (same channel-within-head)
  a0 += __shfl_xor(a0, 16); a0 += __shfl_xor(a0, 32);
  a1 += __shfl_xor(a1, 16); a1 += __shfl_xor(a1, 32);
  a2 += __shfl_xor(a2, 16); a2 += __shfl_xor(a2, 32);
  a3 += __shfl_xor(a3, 16); a3 += __shfl_xor(a3, 32);

  if (lane < 16) {
    float4 b = *(const float4*)(bias + lane * 4);
    ushort4 o;
    o.x = f2bf(fmaxf(0.25f * a0 + b.x, 0.f));
    o.y = f2bf(fmaxf(0.25f * a1 + b.y, 0.f));
    o.z = f2bf(fmaxf(0.25f * a2 + b.z, 0.f));
    o.w = f2bf(fmaxf(0.25f * a3 + b.w, 0.f));
    *(ushort4*)(hout + (size_t)node * 64 + lane * 4) = o;
  }
}

// ---------------- global mean pool (batch is sorted), bf16 in ----------------
__global__ void pool_kernel(const unsigned short* __restrict__ h, const int* __restrict__ batch,
                            float* __restrict__ pool, float* __restrict__ pcnt, int n_nodes) {
  int c = threadIdx.x;  // 64 threads
  int n0 = blockIdx.x * 64;
  int n1 = min(n0 + 64, n_nodes);
  float acc = 0.f;
  int run = 0;
  int gcur = batch[n0];
  for (int n = n0; n < n1; ++n) {
    int g = batch[n];
    if (g != gcur) {
      atomicAdd(&pool[gcur * 64 + c], acc);
      if (c == 0) atomicAdd(&pcnt[gcur], (float)run);
      acc = 0.f; run = 0; gcur = g;
    }
    acc += bf2f(h[(size_t)n * 64 + c]);
    ++run;
  }
  atomicAdd(&pool[gcur * 64 + c], acc);
  if (c == 0) atomicAdd(&pcnt[gcur], (float)run);
}

// ---------------- out = (pool/cnt) @ Wo + bo : [G,64]@[64,32] ----------------
__global__ void out_kernel(const float* __restrict__ pool, const float* __restrict__ pcnt,
                           const float* __restrict__ Wo, const float* __restrict__ bo,
                           float* __restrict__ out, int g_total) {
  int idx = blockIdx.x * blockDim.x + threadIdx.x;
  if (idx >= g_total * 32) return;
  int g = idx >> 5, d = idx & 31;
  float inv = 1.f / fmaxf(pcnt[g], 1.f);
  float acc = bo[d];
#pragma unroll
  for (int c = 0; c < 64; ++c) acc += (pool[g * 64 + c] * inv) * Wo[c * 32 + d];
  out[idx] = acc;
}

extern "C" void kernel_launch(void* const* d_in, const int* in_sizes, int n_in,
                              void* d_out, int out_size, void* d_ws, size_t ws_size,
                              hipStream_t stream) {
  const float* x     = (const float*)d_in[0];
  const int*   ei    = (const int*)d_in[1];
  const int*   batch = (const int*)d_in[2];
  const float* Wp    = (const float*)d_in[3];
  const float* bp    = (const float*)d_in[4];
  const float* Wo    = (const float*)d_in[5];
  const float* bo    = (const float*)d_in[6];
  const float* Wl[3]  = {(const float*)d_in[7],  (const float*)d_in[11], (const float*)d_in[15]};
  const float* Asl[3] = {(const float*)d_in[8],  (const float*)d_in[12], (const float*)d_in[16]};
  const float* Adl[3] = {(const float*)d_in[9],  (const float*)d_in[13], (const float*)d_in[17]};
  const float* Bl[3]  = {(const float*)d_in[10], (const float*)d_in[14], (const float*)d_in[18]};

  const int N = in_sizes[0] / 16;   // 50000
  const int E = in_sizes[1] / 2;    // 800000
  const int G = out_size / 32;      // 64
  const int Et = E + N;             // edges incl. self loops
  const int* src = ei;
  const int* dst = ei + E;
  const int NB = (N + 1023) / 1024; // scan blocks (<=64)

  // workspace carve (256B aligned)
  char* ws = (char*)d_ws;
  size_t off = 0;
  auto take = [&](size_t bytes) -> void* {
    void* p = ws + off;
    off = (off + bytes + 255) & ~(size_t)255;
    return p;
  };
  unsigned short* h_a = (unsigned short*)take((size_t)N * 64 * 2);
  unsigned short* h_b = (unsigned short*)take((size_t)N * 64 * 2);
  unsigned short* hwb = (unsigned short*)take((size_t)N * 256 * 2);
  float* alS   = (float*)take((size_t)N * 4 * 4);
  float* alD   = (float*)take((size_t)N * 4 * 4);
  int*   deg   = (int*)take((size_t)N * 4);
  int*   cnt   = (int*)take((size_t)N * 4);
  int*   rowp  = (int*)take((size_t)(N + 1) * 4);
  int*   col   = (int*)take((size_t)Et * 4);
  int*   bsum  = (int*)take((size_t)64 * 4);
  int*   bpre  = (int*)take((size_t)65 * 4);
  float* Wa    = (float*)take((size_t)3 * 512 * 4);
  unsigned short* Wsw  = (unsigned short*)take((size_t)3 * 16384 * 2);
  unsigned short* Wasw = (unsigned short*)take((size_t)3 * 1024 * 2);
  float* pool  = (float*)take((size_t)G * 64 * 4);
  float* pcnt  = (float*)take((size_t)G * 4);
  (void)ws_size; (void)n_in;

  // fold attention vectors into W, then pre-swizzle to MFMA B-fragment order
  prep_wa3<<<3, 256, 0, stream>>>(Wl[0], Asl[0], Adl[0], Wl[1], Asl[1], Adl[1],
                                  Wl[2], Asl[2], Adl[2], Wa);
  prep_wsw<<<3, 256, 0, stream>>>(Wl[0], Wl[1], Wl[2], Wa, Wsw, Wasw);

  // CSR build (self-loop +1 folded into scan_a; init_csr folded into scan_c)
  hipMemsetAsync(deg, 0, (size_t)N * 4, stream);
  hist_kernel<<<(E + 255) / 256, 256, 0, stream>>>(dst, deg, E);
  scan_a<<<NB, 256, 0, stream>>>(deg, rowp, bsum, N);
  scan_b<<<1, 64, 0, stream>>>(bsum, bpre, NB);
  scan_c<<<(N + 255) / 256, 256, 0, stream>>>(rowp, bpre, cnt, col, N);
  scatter_kernel<<<(E + 255) / 256, 256, 0, stream>>>(src, dst, rowp, cnt, col, E);

  // input projection
  proj_kernel<<<((size_t)N * 64 + 255) / 256, 256, 0, stream>>>(x, Wp, bp, h_a, N);

  // 3 GAT layers
  const unsigned short* hin = h_a;
  unsigned short* hout = h_b;
  for (int l = 0; l < 3; ++l) {
    hw_kernel<<<(N + 63) / 64, 256, 0, stream>>>(hin, Wsw + (size_t)l * 16384,
                                                 Wasw + (size_t)l * 1024, hwb, alS, alD, N);
    gat_agg<<<(N + 3) / 4, 256, 0, stream>>>(rowp, col, alS, alD, hwb, Bl[l], hout, N);
    const unsigned short* tmp = hout;
    hout = (unsigned short*)hin;
    hin = tmp;
  }

  // pooling + output projection
  hipMemsetAsync(pool, 0, (size_t)G * 64 * 4, stream);
  hipMemsetAsync(pcnt, 0, (size_t)G * 4, stream);
  pool_kernel<<<(N + 63) / 64, 64, 0, stream>>>(hin, batch, pool, pcnt, N);
  out_kernel<<<(G * 32 + 255) / 256, 256, 0, stream>>>(pool, pcnt, Wo, bo, (float*)d_out, G);
}

// Round 8
// 413.284 us; speedup vs baseline: 2.4944x; 1.0735x over previous
//
#include <hip/hip_runtime.h>

#define NEG_SLOPE 0.2f

typedef __attribute__((ext_vector_type(8))) short bf16x8;
typedef __attribute__((ext_vector_type(4))) float f32x4;

__device__ __forceinline__ float lrelu(float x) { return fmaxf(x, NEG_SLOPE * x); }

__device__ __forceinline__ float bf2f(unsigned short u) {
  return __uint_as_float(((unsigned int)u) << 16);
}
__device__ __forceinline__ unsigned short f2bf(float f) {
  unsigned int u = __float_as_uint(f);
  u += 0x7fffu + ((u >> 16) & 1u);   // round-to-nearest-even
  return (unsigned short)(u >> 16);
}

// ---------------- h0 = relu(x @ Wp + bp) : [N,16]@[16,64], bf16 out ----------------
__global__ void proj_kernel(const float* __restrict__ x, const float* __restrict__ Wp,
                            const float* __restrict__ bp, unsigned short* __restrict__ h,
                            int n_nodes) {
  int idx = blockIdx.x * blockDim.x + threadIdx.x;
  int n = idx >> 6, c = idx & 63;
  if (n >= n_nodes) return;
  float acc = bp[c];
#pragma unroll
  for (int k = 0; k < 16; ++k) acc += x[n * 16 + k] * Wp[k * 64 + c];
  h[n * 64 + c] = f2bf(fmaxf(acc, 0.f));
}

// ---------------- CSR build (by destination), self-loop first ----------------
__global__ void hist_kernel(const int* __restrict__ dst, int* __restrict__ deg, int e) {
  int i = blockIdx.x * blockDim.x + threadIdx.x;
  if (i < e) atomicAdd(&deg[dst[i]], 1);
}

// phase A: per-block (1024 elems) local exclusive scan of (deg[i]+1); block sums out.
__global__ __launch_bounds__(256) void scan_a(const int* __restrict__ deg, int* __restrict__ rowp,
                                              int* __restrict__ bsum, int n) {
  __shared__ int s[256];
  int t = threadIdx.x;
  int base = blockIdx.x * 1024 + t * 4;
  int d0 = (base + 0 < n) ? deg[base + 0] + 1 : 0;
  int d1 = (base + 1 < n) ? deg[base + 1] + 1 : 0;
  int d2 = (base + 2 < n) ? deg[base + 2] + 1 : 0;
  int d3 = (base + 3 < n) ? deg[base + 3] + 1 : 0;
  s[t] = d0 + d1 + d2 + d3;
  __syncthreads();
  for (int off = 1; off < 256; off <<= 1) {
    int v = 0;
    if (t >= off) v = s[t - off];
    __syncthreads();
    if (t >= off) s[t] += v;
    __syncthreads();
  }
  int p = (t == 0) ? 0 : s[t - 1];
  if (base + 0 < n) rowp[base + 0] = p;
  p += d0;
  if (base + 1 < n) rowp[base + 1] = p;
  p += d1;
  if (base + 2 < n) rowp[base + 2] = p;
  p += d2;
  if (base + 3 < n) rowp[base + 3] = p;
  if (t == 255) bsum[blockIdx.x] = s[255];
}

// phase B: single wave exclusive-scans <=64 block sums; bpre[64] = grand total.
__global__ void scan_b(const int* __restrict__ bsum, int* __restrict__ bpre, int nb) {
  int t = threadIdx.x;  // 64 threads = 1 wave
  int v = (t < nb) ? bsum[t] : 0;
  int orig = v;
#pragma unroll
  for (int off = 1; off < 64; off <<= 1) {
    int u = __shfl_up(v, off);
    if (t >= off) v += u;
  }
  bpre[t] = v - orig;
  if (t == 63) bpre[64] = v;
}

// phase C: add block prefixes; fused init_csr (self-loop slot 0).
__global__ void scan_c(int* __restrict__ rowp, const int* __restrict__ bpre,
                       int* __restrict__ cnt, int* __restrict__ col, int n) {
  int i = blockIdx.x * blockDim.x + threadIdx.x;
  if (i < n) {
    int r = rowp[i] + bpre[i >> 10];
    rowp[i] = r;
    cnt[i] = 1;       // slot 0 = self loop
    col[r] = i;
  }
  if (i == 0) rowp[n] = bpre[64];
}

__global__ void scatter_kernel(const int* __restrict__ src, const int* __restrict__ dst,
                               const int* __restrict__ rowp, int* __restrict__ cnt,
                               int* __restrict__ col, int e) {
  int i = blockIdx.x * blockDim.x + threadIdx.x;
  if (i < e) {
    int d = dst[i];
    int pos = rowp[d] + atomicAdd(&cnt[d], 1);
    col[pos] = src[i];
  }
}

// ---------------- fold a_src/a_dst into W: Wa[l][k][o] (o<4: src head o; o>=4: dst head o-4) ----
__global__ void prep_wa3(const float* __restrict__ W0, const float* __restrict__ as0, const float* __restrict__ ad0,
                         const float* __restrict__ W1, const float* __restrict__ as1, const float* __restrict__ ad1,
                         const float* __restrict__ W2, const float* __restrict__ as2, const float* __restrict__ ad2,
                         float* __restrict__ Wa) {
  int l = blockIdx.x;
  const float* W  = l == 0 ? W0  : l == 1 ? W1  : W2;
  const float* as = l == 0 ? as0 : l == 1 ? as1 : as2;
  const float* ad = l == 0 ? ad0 : l == 1 ? ad1 : ad2;
  int t = threadIdx.x;          // 256 threads
  int k = t >> 2, h = t & 3;
  float ss = 0.f, sd = 0.f;
  for (int c = 0; c < 64; ++c) {
    float w = W[k * 256 + h * 64 + c];
    ss += w * as[h * 64 + c];
    sd += w * ad[h * 64 + c];
  }
  Wa[l * 512 + k * 8 + h] = ss;
  Wa[l * 512 + k * 8 + 4 + h] = sd;
}

// ---------------- pre-swizzle W (and Wa) into MFMA B-fragment order, bf16 ----------------
__global__ void prep_wsw(const float* __restrict__ W0, const float* __restrict__ W1,
                         const float* __restrict__ W2, const float* __restrict__ Wa,
                         unsigned short* __restrict__ Wsw, unsigned short* __restrict__ Wasw) {
  int l = blockIdx.x;
  const float* W = l == 0 ? W0 : l == 1 ? W1 : W2;
  int t = threadIdx.x;  // 256
  for (int s = t; s < 2048; s += 256) {
    int nt = s >> 7, kk = (s >> 6) & 1, lane = s & 63;
    int kq = lane >> 4, r = lane & 15;
#pragma unroll
    for (int j = 0; j < 8; ++j) {
      int k = kk * 32 + kq * 8 + j;
      Wsw[(size_t)l * 16384 + (size_t)s * 8 + j] = f2bf(W[k * 256 + nt * 16 + r]);
    }
  }
  if (t < 128) {
    int lane = t & 63, kq = lane >> 4, r = lane & 15;
    int kk = t >> 6;
#pragma unroll
    for (int j = 0; j < 8; ++j) {
      int k = kk * 32 + kq * 8 + j;
      float v = (r < 8) ? Wa[l * 512 + k * 8 + r] : 0.f;
      Wasw[l * 1024 + t * 8 + j] = f2bf(v);
    }
  }
}

// ---------------- hw(bf16) = h @ W via MFMA + attention logits ----------------
__global__ __launch_bounds__(256) void hw_kernel(const unsigned short* __restrict__ hb,
                                                 const unsigned short* __restrict__ Wsw,
                                                 const unsigned short* __restrict__ Wasw,
                                                 unsigned short* __restrict__ hwb,
                                                 float* __restrict__ al_s, float* __restrict__ al_d,
                                                 int n_nodes) {
  int t = threadIdx.x;
  int w = t >> 6, lane = t & 63;
  int kq = lane >> 4, r16 = lane & 15;
  int n0 = blockIdx.x << 6;

  // A fragments: 4 m-tiles x 2 k-steps; direct 16B loads from row-major bf16 h
  bf16x8 a[4][2];
#pragma unroll
  for (int m = 0; m < 4; ++m) {
    int row = min(n0 + m * 16 + r16, n_nodes - 1);
    const unsigned short* p = hb + (size_t)row * 64 + kq * 8;
    a[m][0] = *(const bf16x8*)(p);
    a[m][1] = *(const bf16x8*)(p + 32);
  }
  // B fragments: 4 local n-tiles x 2 k-steps
  bf16x8 b[4][2];
#pragma unroll
  for (int nt = 0; nt < 4; ++nt) {
    int ntg = w * 4 + nt;
    const unsigned short* p = Wsw + ((size_t)ntg * 128 + lane) * 8;
    b[nt][0] = *(const bf16x8*)(p);
    b[nt][1] = *(const bf16x8*)(p + 512);
  }

  f32x4 acc[4][4];
#pragma unroll
  for (int m = 0; m < 4; ++m)
#pragma unroll
    for (int nt = 0; nt < 4; ++nt) acc[m][nt] = (f32x4){0.f, 0.f, 0.f, 0.f};

#pragma unroll
  for (int m = 0; m < 4; ++m)
#pragma unroll
    for (int nt = 0; nt < 4; ++nt) {
      acc[m][nt] = __builtin_amdgcn_mfma_f32_16x16x32_bf16(a[m][0], b[nt][0], acc[m][nt], 0, 0, 0);
      acc[m][nt] = __builtin_amdgcn_mfma_f32_16x16x32_bf16(a[m][1], b[nt][1], acc[m][nt], 0, 0, 0);
    }

  // store hw as bf16: C/D mapping col=lane&15, row=(lane>>4)*4+reg
#pragma unroll
  for (int m = 0; m < 4; ++m) {
#pragma unroll
    for (int j = 0; j < 4; ++j) {
      int row = n0 + m * 16 + kq * 4 + j;
      if (row < n_nodes) {
#pragma unroll
        for (int nt = 0; nt < 4; ++nt) {
          int col = (w * 4 + nt) * 16 + r16;
          hwb[(size_t)row * 256 + col] = f2bf(acc[m][nt][j]);
        }
      }
    }
  }

  // attention logits: wave w handles m-tile w; B = folded Wa (8 valid cols)
  bf16x8 ba0 = *(const bf16x8*)(Wasw + lane * 8);
  bf16x8 ba1 = *(const bf16x8*)(Wasw + (64 + lane) * 8);
  f32x4 accl = (f32x4){0.f, 0.f, 0.f, 0.f};
  accl = __builtin_amdgcn_mfma_f32_16x16x32_bf16(a[w][0], ba0, accl, 0, 0, 0);
  accl = __builtin_amdgcn_mfma_f32_16x16x32_bf16(a[w][1], ba1, accl, 0, 0, 0);
  if (r16 < 8) {
#pragma unroll
    for (int j = 0; j < 4; ++j) {
      int row = n0 + w * 16 + kq * 4 + j;
      if (row < n_nodes) {
        if (r16 < 4) al_s[row * 4 + r16] = accl[j];
        else         al_d[row * 4 + (r16 - 4)] = accl[j];
      }
    }
  }
}

// ---------------- aggregate: wave per node, two-phase wave-synchronous ----------------
// Phase 1 (lane-parallel, 64 edges/chunk): coalesced col load, alS float4 load, all-head
// w=exp(lrelu(.)), write (gather_byte_addr, w) pairs to LDS (addr duplicated per head).
// Phase 2 (per edge): one ds_read_b64 -> (addr, w_head); independent 8B/lane gather; 4 FMA.
__global__ __launch_bounds__(256) void gat_agg(const int* __restrict__ rowp, const int* __restrict__ col,
                                               const float* __restrict__ alS, const float* __restrict__ alD,
                                               const unsigned short* __restrict__ hwb,
                                               const float* __restrict__ bias,
                                               unsigned short* __restrict__ hout,
                                               int n_nodes) {
  __shared__ uint2 pw[4][64 * 4];   // [wave][edge*4 + head] = (byte addr, w)
  int t = threadIdx.x;
  int wslot = t >> 6, lane = t & 63;
  int node = blockIdx.x * 4 + wslot;
  if (node >= n_nodes) return;      // whole wave exits together
  int base = rowp[node];
  int degv = rowp[node + 1] - base;
  int head = lane >> 4;
  unsigned int laneoff = (unsigned int)lane << 3;   // 8B per lane within 512B row
  float4 ald4 = *(const float4*)(alD + (size_t)node * 4);

  float a0 = 0.f, a1 = 0.f, a2 = 0.f, a3 = 0.f, denom = 0.f;

  for (int c0 = 0; c0 < degv; c0 += 64) {
    int cnt = min(64, degv - c0);
    if (lane < cnt) {
      int s = col[base + c0 + lane];                  // coalesced
      float4 as4 = *(const float4*)(alS + (size_t)s * 4);
      unsigned int ab = (unsigned int)s << 9;         // byte addr of hwb row
      float w0 = __expf(lrelu(as4.x + ald4.x));
      float w1 = __expf(lrelu(as4.y + ald4.y));
      float w2 = __expf(lrelu(as4.z + ald4.z));
      float w3 = __expf(lrelu(as4.w + ald4.w));
      pw[wslot][lane * 4 + 0] = make_uint2(ab, __float_as_uint(w0));
      pw[wslot][lane * 4 + 1] = make_uint2(ab, __float_as_uint(w1));
      pw[wslot][lane * 4 + 2] = make_uint2(ab, __float_as_uint(w2));
      pw[wslot][lane * 4 + 3] = make_uint2(ab, __float_as_uint(w3));
    }
    // wave-synchronous: same wave wrote, same wave reads; HW keeps DS ops in order,
    // compiler inserts lgkmcnt waits before use.
#pragma unroll 4
    for (int i = 0; i < cnt; ++i) {
      uint2 p = pw[wslot][i * 4 + head];              // one ds_read_b64
      float w = __uint_as_float(p.y);
      uint2 v = *(const uint2*)((const char*)hwb + (p.x + laneoff));  // independent gather
      denom += w;
      a0 += w * __uint_as_float(v.x << 16);
      a1 += w * __uint_as_float(v.x & 0xffff0000u);
      a2 += w * __uint_as_float(v.y << 16);
      a3 += w * __uint_as_float(v.y & 0xffff0000u);
    }
  }

  float inv = 1.f / denom;          // per-head softmax normalization
  a0 *= inv; a1 *= inv; a2 *= inv; a3 *= inv;

  // head mean: sum lanes {l, l^16, l^32, l^48} (same channel-within-head)
  a0 += __shfl_xor(a0, 16); a0 += __shfl_xor(a0, 32);
  a1 += __shfl_xor(a1, 16); a1 += __shfl_xor(a1, 32);
  a2 += __shfl_xor(a2, 16); a2 += __shfl_xor(a2, 32);
  a3 += __shfl_xor(a3, 16); a3 += __shfl_xor(a3, 32);

  if (lane < 16) {
    float4 b = *(const float4*)(bias + lane * 4);
    ushort4 o;
    o.x = f2bf(fmaxf(0.25f * a0 + b.x, 0.f));
    o.y = f2bf(fmaxf(0.25f * a1 + b.y, 0.f));
    o.z = f2bf(fmaxf(0.25f * a2 + b.z, 0.f));
    o.w = f2bf(fmaxf(0.25f * a3 + b.w, 0.f));
    *(ushort4*)(hout + (size_t)node * 64 + lane * 4) = o;
  }
}

// ---------------- global mean pool (batch is sorted), bf16 in ----------------
__global__ void pool_kernel(const unsigned short* __restrict__ h, const int* __restrict__ batch,
                            float* __restrict__ pool, float* __restrict__ pcnt, int n_nodes) {
  int c = threadIdx.x;  // 64 threads
  int n0 = blockIdx.x * 64;
  int n1 = min(n0 + 64, n_nodes);
  float acc = 0.f;
  int run = 0;
  int gcur = batch[n0];
  for (int n = n0; n < n1; ++n) {
    int g = batch[n];
    if (g != gcur) {
      atomicAdd(&pool[gcur * 64 + c], acc);
      if (c == 0) atomicAdd(&pcnt[gcur], (float)run);
      acc = 0.f; run = 0; gcur = g;
    }
    acc += bf2f(h[(size_t)n * 64 + c]);
    ++run;
  }
  atomicAdd(&pool[gcur * 64 + c], acc);
  if (c == 0) atomicAdd(&pcnt[gcur], (float)run);
}

// ---------------- out = (pool/cnt) @ Wo + bo : [G,64]@[64,32] ----------------
__global__ void out_kernel(const float* __restrict__ pool, const float* __restrict__ pcnt,
                           const float* __restrict__ Wo, const float* __restrict__ bo,
                           float* __restrict__ out, int g_total) {
  int idx = blockIdx.x * blockDim.x + threadIdx.x;
  if (idx >= g_total * 32) return;
  int g = idx >> 5, d = idx & 31;
  float inv = 1.f / fmaxf(pcnt[g], 1.f);
  float acc = bo[d];
#pragma unroll
  for (int c = 0; c < 64; ++c) acc += (pool[g * 64 + c] * inv) * Wo[c * 32 + d];
  out[idx] = acc;
}

extern "C" void kernel_launch(void* const* d_in, const int* in_sizes, int n_in,
                              void* d_out, int out_size, void* d_ws, size_t ws_size,
                              hipStream_t stream) {
  const float* x     = (const float*)d_in[0];
  const int*   ei    = (const int*)d_in[1];
  const int*   batch = (const int*)d_in[2];
  const float* Wp    = (const float*)d_in[3];
  const float* bp    = (const float*)d_in[4];
  const float* Wo    = (const float*)d_in[5];
  const float* bo    = (const float*)d_in[6];
  const float* Wl[3]  = {(const float*)d_in[7],  (const float*)d_in[11], (const float*)d_in[15]};
  const float* Asl[3] = {(const float*)d_in[8],  (const float*)d_in[12], (const float*)d_in[16]};
  const float* Adl[3] = {(const float*)d_in[9],  (const float*)d_in[13], (const float*)d_in[17]};
  const float* Bl[3]  = {(const float*)d_in[10], (const float*)d_in[14], (const float*)d_in[18]};

  const int N = in_sizes[0] / 16;   // 50000
  const int E = in_sizes[1] / 2;    // 800000
  const int G = out_size / 32;      // 64
  const int Et = E + N;             // edges incl. self loops
  const int* src = ei;
  const int* dst = ei + E;
  const int NB = (N + 1023) / 1024; // scan blocks (<=64)

  // workspace carve (256B aligned)
  char* ws = (char*)d_ws;
  size_t off = 0;
  auto take = [&](size_t bytes) -> void* {
    void* p = ws + off;
    off = (off + bytes + 255) & ~(size_t)255;
    return p;
  };
  unsigned short* h_a = (unsigned short*)take((size_t)N * 64 * 2);
  unsigned short* h_b = (unsigned short*)take((size_t)N * 64 * 2);
  unsigned short* hwb = (unsigned short*)take((size_t)N * 256 * 2);
  float* alS   = (float*)take((size_t)N * 4 * 4);
  float* alD   = (float*)take((size_t)N * 4 * 4);
  int*   deg   = (int*)take((size_t)N * 4);
  int*   cnt   = (int*)take((size_t)N * 4);
  int*   rowp  = (int*)take((size_t)(N + 1) * 4);
  int*   col   = (int*)take((size_t)Et * 4);
  int*   bsum  = (int*)take((size_t)64 * 4);
  int*   bpre  = (int*)take((size_t)65 * 4);
  float* Wa    = (float*)take((size_t)3 * 512 * 4);
  unsigned short* Wsw  = (unsigned short*)take((size_t)3 * 16384 * 2);
  unsigned short* Wasw = (unsigned short*)take((size_t)3 * 1024 * 2);
  float* pool  = (float*)take((size_t)G * 64 * 4);
  float* pcnt  = (float*)take((size_t)G * 4);
  (void)ws_size; (void)n_in;

  // fold attention vectors into W, then pre-swizzle to MFMA B-fragment order
  prep_wa3<<<3, 256, 0, stream>>>(Wl[0], Asl[0], Adl[0], Wl[1], Asl[1], Adl[1],
                                  Wl[2], Asl[2], Adl[2], Wa);
  prep_wsw<<<3, 256, 0, stream>>>(Wl[0], Wl[1], Wl[2], Wa, Wsw, Wasw);

  // CSR build (self-loop +1 folded into scan_a; init_csr folded into scan_c)
  hipMemsetAsync(deg, 0, (size_t)N * 4, stream);
  hist_kernel<<<(E + 255) / 256, 256, 0, stream>>>(dst, deg, E);
  scan_a<<<NB, 256, 0, stream>>>(deg, rowp, bsum, N);
  scan_b<<<1, 64, 0, stream>>>(bsum, bpre, NB);
  scan_c<<<(N + 255) / 256, 256, 0, stream>>>(rowp, bpre, cnt, col, N);
  scatter_kernel<<<(E + 255) / 256, 256, 0, stream>>>(src, dst, rowp, cnt, col, E);

  // input projection
  proj_kernel<<<((size_t)N * 64 + 255) / 256, 256, 0, stream>>>(x, Wp, bp, h_a, N);

  // 3 GAT layers
  const unsigned short* hin = h_a;
  unsigned short* hout = h_b;
  for (int l = 0; l < 3; ++l) {
    hw_kernel<<<(N + 63) / 64, 256, 0, stream>>>(hin, Wsw + (size_t)l * 16384,
                                                 Wasw + (size_t)l * 1024, hwb, alS, alD, N);
    gat_agg<<<(N + 3) / 4, 256, 0, stream>>>(rowp, col, alS, alD, hwb, Bl[l], hout, N);
    const unsigned short* tmp = hout;
    hout = (unsigned short*)hin;
    hin = tmp;
  }

  // pooling + output projection
  hipMemsetAsync(pool, 0, (size_t)G * 64 * 4, stream);
  hipMemsetAsync(pcnt, 0, (size_t)G * 4, stream);
  pool_kernel<<<(N + 63) / 64, 64, 0, stream>>>(hin, batch, pool, pcnt, N);
  out_kernel<<<(G * 32 + 255) / 256, 256, 0, stream>>>(pool, pcnt, Wo, bo, (float*)d_out, G);
}

// Round 9
// 410.395 us; speedup vs baseline: 2.5119x; 1.0070x over previous
//
#include <hip/hip_runtime.h>

#define NEG_SLOPE 0.2f

typedef __attribute__((ext_vector_type(8))) short bf16x8;
typedef __attribute__((ext_vector_type(4))) float f32x4;

__device__ __forceinline__ float lrelu(float x) { return fmaxf(x, NEG_SLOPE * x); }

__device__ __forceinline__ float bf2f(unsigned short u) {
  return __uint_as_float(((unsigned int)u) << 16);
}
__device__ __forceinline__ unsigned short f2bf(float f) {
  unsigned int u = __float_as_uint(f);
  u += 0x7fffu + ((u >> 16) & 1u);   // round-to-nearest-even
  return (unsigned short)(u >> 16);
}

// ---------------- h0 = relu(x @ Wp + bp) : [N,16]@[16,64], bf16 out ----------------
__global__ void proj_kernel(const float* __restrict__ x, const float* __restrict__ Wp,
                            const float* __restrict__ bp, unsigned short* __restrict__ h,
                            int n_nodes) {
  int idx = blockIdx.x * blockDim.x + threadIdx.x;
  int n = idx >> 6, c = idx & 63;
  if (n >= n_nodes) return;
  float acc = bp[c];
#pragma unroll
  for (int k = 0; k < 16; ++k) acc += x[n * 16 + k] * Wp[k * 64 + c];
  h[n * 64 + c] = f2bf(fmaxf(acc, 0.f));
}

// ---------------- CSR build (by destination), self-loop first ----------------
__global__ void hist_kernel(const int* __restrict__ dst, int* __restrict__ deg, int e) {
  int i = blockIdx.x * blockDim.x + threadIdx.x;
  if (i < e) atomicAdd(&deg[dst[i]], 1);
}

// phase A: per-block (1024 elems) local exclusive scan of (deg[i]+1); block sums out.
__global__ __launch_bounds__(256) void scan_a(const int* __restrict__ deg, int* __restrict__ rowp,
                                              int* __restrict__ bsum, int n) {
  __shared__ int s[256];
  int t = threadIdx.x;
  int base = blockIdx.x * 1024 + t * 4;
  int d0 = (base + 0 < n) ? deg[base + 0] + 1 : 0;
  int d1 = (base + 1 < n) ? deg[base + 1] + 1 : 0;
  int d2 = (base + 2 < n) ? deg[base + 2] + 1 : 0;
  int d3 = (base + 3 < n) ? deg[base + 3] + 1 : 0;
  s[t] = d0 + d1 + d2 + d3;
  __syncthreads();
  for (int off = 1; off < 256; off <<= 1) {
    int v = 0;
    if (t >= off) v = s[t - off];
    __syncthreads();
    if (t >= off) s[t] += v;
    __syncthreads();
  }
  int p = (t == 0) ? 0 : s[t - 1];
  if (base + 0 < n) rowp[base + 0] = p;
  p += d0;
  if (base + 1 < n) rowp[base + 1] = p;
  p += d1;
  if (base + 2 < n) rowp[base + 2] = p;
  p += d2;
  if (base + 3 < n) rowp[base + 3] = p;
  if (t == 255) bsum[blockIdx.x] = s[255];
}

// phase B: single wave exclusive-scans <=64 block sums; bpre[64] = grand total.
__global__ void scan_b(const int* __restrict__ bsum, int* __restrict__ bpre, int nb) {
  int t = threadIdx.x;  // 64 threads = 1 wave
  int v = (t < nb) ? bsum[t] : 0;
  int orig = v;
#pragma unroll
  for (int off = 1; off < 64; off <<= 1) {
    int u = __shfl_up(v, off);
    if (t >= off) v += u;
  }
  bpre[t] = v - orig;
  if (t == 63) bpre[64] = v;
}

// phase C: add block prefixes; fused init_csr (self-loop slot 0).
__global__ void scan_c(int* __restrict__ rowp, const int* __restrict__ bpre,
                       int* __restrict__ cnt, int* __restrict__ col, int n) {
  int i = blockIdx.x * blockDim.x + threadIdx.x;
  if (i < n) {
    int r = rowp[i] + bpre[i >> 10];
    rowp[i] = r;
    cnt[i] = 1;       // slot 0 = self loop
    col[r] = i;
  }
  if (i == 0) rowp[n] = bpre[64];
}

__global__ void scatter_kernel(const int* __restrict__ src, const int* __restrict__ dst,
                               const int* __restrict__ rowp, int* __restrict__ cnt,
                               int* __restrict__ col, int e) {
  int i = blockIdx.x * blockDim.x + threadIdx.x;
  if (i < e) {
    int d = dst[i];
    int pos = rowp[d] + atomicAdd(&cnt[d], 1);
    col[pos] = src[i];
  }
}

// ---------------- fused: fold a_src/a_dst into W, then swizzle W & Wa to MFMA B-frag (bf16) ----
// Wsw layout: [layer][nt*128 + kk*64 + lane][8]; Wasw: [layer][kk*64 + lane][8] (cols 0..7)
__global__ __launch_bounds__(256) void prep_kernel(
    const float* __restrict__ W0, const float* __restrict__ as0, const float* __restrict__ ad0,
    const float* __restrict__ W1, const float* __restrict__ as1, const float* __restrict__ ad1,
    const float* __restrict__ W2, const float* __restrict__ as2, const float* __restrict__ ad2,
    unsigned short* __restrict__ Wsw, unsigned short* __restrict__ Wasw) {
  __shared__ float wa[512];
  int l = blockIdx.x;
  const float* W  = l == 0 ? W0  : l == 1 ? W1  : W2;
  const float* as = l == 0 ? as0 : l == 1 ? as1 : as2;
  const float* ad = l == 0 ? ad0 : l == 1 ? ad1 : ad2;
  int t = threadIdx.x;          // 256 threads
  {
    int k = t >> 2, h = t & 3;
    float ss = 0.f, sd = 0.f;
    for (int c = 0; c < 64; ++c) {
      float w = W[k * 256 + h * 64 + c];
      ss += w * as[h * 64 + c];
      sd += w * ad[h * 64 + c];
    }
    wa[k * 8 + h] = ss;
    wa[k * 8 + 4 + h] = sd;
  }
  __syncthreads();
  for (int s = t; s < 2048; s += 256) {
    int nt = s >> 7, kk = (s >> 6) & 1, lane = s & 63;
    int kq = lane >> 4, r = lane & 15;
#pragma unroll
    for (int j = 0; j < 8; ++j) {
      int k = kk * 32 + kq * 8 + j;
      Wsw[(size_t)l * 16384 + (size_t)s * 8 + j] = f2bf(W[k * 256 + nt * 16 + r]);
    }
  }
  if (t < 128) {
    int lane = t & 63, kq = lane >> 4, r = lane & 15;
    int kk = t >> 6;
#pragma unroll
    for (int j = 0; j < 8; ++j) {
      int k = kk * 32 + kq * 8 + j;
      float v = (r < 8) ? wa[k * 8 + r] : 0.f;
      Wasw[l * 1024 + t * 8 + j] = f2bf(v);
    }
  }
}

// ---------------- hw(bf16) = h @ W via MFMA + attention logits ----------------
__global__ __launch_bounds__(256) void hw_kernel(const unsigned short* __restrict__ hb,
                                                 const unsigned short* __restrict__ Wsw,
                                                 const unsigned short* __restrict__ Wasw,
                                                 unsigned short* __restrict__ hwb,
                                                 float* __restrict__ al_s, float* __restrict__ al_d,
                                                 int n_nodes) {
  int t = threadIdx.x;
  int w = t >> 6, lane = t & 63;
  int kq = lane >> 4, r16 = lane & 15;
  int n0 = blockIdx.x << 6;

  // A fragments: 4 m-tiles x 2 k-steps; direct 16B loads from row-major bf16 h
  bf16x8 a[4][2];
#pragma unroll
  for (int m = 0; m < 4; ++m) {
    int row = min(n0 + m * 16 + r16, n_nodes - 1);
    const unsigned short* p = hb + (size_t)row * 64 + kq * 8;
    a[m][0] = *(const bf16x8*)(p);
    a[m][1] = *(const bf16x8*)(p + 32);
  }
  // B fragments: 4 local n-tiles x 2 k-steps
  bf16x8 b[4][2];
#pragma unroll
  for (int nt = 0; nt < 4; ++nt) {
    int ntg = w * 4 + nt;
    const unsigned short* p = Wsw + ((size_t)ntg * 128 + lane) * 8;
    b[nt][0] = *(const bf16x8*)(p);
    b[nt][1] = *(const bf16x8*)(p + 512);
  }

  f32x4 acc[4][4];
#pragma unroll
  for (int m = 0; m < 4; ++m)
#pragma unroll
    for (int nt = 0; nt < 4; ++nt) acc[m][nt] = (f32x4){0.f, 0.f, 0.f, 0.f};

#pragma unroll
  for (int m = 0; m < 4; ++m)
#pragma unroll
    for (int nt = 0; nt < 4; ++nt) {
      acc[m][nt] = __builtin_amdgcn_mfma_f32_16x16x32_bf16(a[m][0], b[nt][0], acc[m][nt], 0, 0, 0);
      acc[m][nt] = __builtin_amdgcn_mfma_f32_16x16x32_bf16(a[m][1], b[nt][1], acc[m][nt], 0, 0, 0);
    }

  // store hw as bf16: C/D mapping col=lane&15, row=(lane>>4)*4+reg
#pragma unroll
  for (int m = 0; m < 4; ++m) {
#pragma unroll
    for (int j = 0; j < 4; ++j) {
      int row = n0 + m * 16 + kq * 4 + j;
      if (row < n_nodes) {
#pragma unroll
        for (int nt = 0; nt < 4; ++nt) {
          int col = (w * 4 + nt) * 16 + r16;
          hwb[(size_t)row * 256 + col] = f2bf(acc[m][nt][j]);
        }
      }
    }
  }

  // attention logits: wave w handles m-tile w; B = folded Wa (8 valid cols)
  bf16x8 ba0 = *(const bf16x8*)(Wasw + lane * 8);
  bf16x8 ba1 = *(const bf16x8*)(Wasw + (64 + lane) * 8);
  f32x4 accl = (f32x4){0.f, 0.f, 0.f, 0.f};
  accl = __builtin_amdgcn_mfma_f32_16x16x32_bf16(a[w][0], ba0, accl, 0, 0, 0);
  accl = __builtin_amdgcn_mfma_f32_16x16x32_bf16(a[w][1], ba1, accl, 0, 0, 0);
  if (r16 < 8) {
#pragma unroll
    for (int j = 0; j < 4; ++j) {
      int row = n0 + w * 16 + kq * 4 + j;
      if (row < n_nodes) {
        if (r16 < 4) al_s[row * 4 + r16] = accl[j];
        else         al_d[row * 4 + (r16 - 4)] = accl[j];
      }
    }
  }
}

// ---------------- aggregate: wave per node, two edges per iteration ----------------
// Phase 1 (lane-parallel, 64 edges/chunk): coalesced col, alS float4, all-head
// w=exp(lrelu(.)), (addr,w) pairs to LDS; slots >= cnt zero-filled (dummy: addr 0, w 0).
// Phase 2: lanes 0-31 = edge 2i (16B/lane), lanes 32-63 = edge 2i+1; 1 ds_read_b64 +
// 1 dwordx4 gather + 8 unpack-FMA per edge-pair per lane; unroll 4 = 8 edges in flight.
__global__ __launch_bounds__(256) void gat_agg(const int* __restrict__ rowp, const int* __restrict__ col,
                                               const float* __restrict__ alS, const float* __restrict__ alD,
                                               const unsigned short* __restrict__ hwb,
                                               const float* __restrict__ bias,
                                               unsigned short* __restrict__ hout,
                                               int n_nodes) {
  __shared__ uint2 pw[4][64 * 4];   // [wave][edge*4 + head] = (byte addr, w)
  int t = threadIdx.x;
  int wslot = t >> 6, lane = t & 63;
  int node = blockIdx.x * 4 + wslot;
  if (node >= n_nodes) return;      // whole wave exits together
  int base = rowp[node];
  int degv = rowp[node + 1] - base;
  int l31 = lane & 31;
  int half = lane >> 5;                               // which edge of the pair
  int headw = l31 >> 3;                               // head owning this lane's 8 channels
  unsigned int laneoff = (unsigned int)l31 << 4;      // 16B per lane within 512B row
  float4 ald4 = *(const float4*)(alD + (size_t)node * 4);

  float a0 = 0.f, a1 = 0.f, a2 = 0.f, a3 = 0.f;
  float a4 = 0.f, a5 = 0.f, a6 = 0.f, a7 = 0.f, denom = 0.f;

  for (int c0 = 0; c0 < degv; c0 += 64) {
    int cnt = min(64, degv - c0);
    {
      unsigned int ab = 0u;
      float w0 = 0.f, w1 = 0.f, w2 = 0.f, w3 = 0.f;
      if (lane < cnt) {
        int s = col[base + c0 + lane];                // coalesced
        float4 as4 = *(const float4*)(alS + (size_t)s * 4);
        ab = (unsigned int)s << 9;                    // byte addr of hwb row
        w0 = __expf(lrelu(as4.x + ald4.x));
        w1 = __expf(lrelu(as4.y + ald4.y));
        w2 = __expf(lrelu(as4.z + ald4.z));
        w3 = __expf(lrelu(as4.w + ald4.w));
      }
      uint4* pd = (uint4*)&pw[wslot][lane * 4];
      pd[0] = make_uint4(ab, __float_as_uint(w0), ab, __float_as_uint(w1));
      pd[1] = make_uint4(ab, __float_as_uint(w2), ab, __float_as_uint(w3));
    }
    // wave-synchronous: same wave wrote, same wave reads (lgkmcnt auto-inserted)
    int iters = (cnt + 1) >> 1;
#pragma unroll 4
    for (int i = 0; i < iters; ++i) {
      int e = i * 2 + half;
      uint2 p = pw[wslot][e * 4 + headw];             // one ds_read_b64
      float w = __uint_as_float(p.y);
      uint4 v = *(const uint4*)((const char*)hwb + (p.x + laneoff));  // independent gather
      denom += w;
      a0 += w * __uint_as_float(v.x << 16);
      a1 += w * __uint_as_float(v.x & 0xffff0000u);
      a2 += w * __uint_as_float(v.y << 16);
      a3 += w * __uint_as_float(v.y & 0xffff0000u);
      a4 += w * __uint_as_float(v.z << 16);
      a5 += w * __uint_as_float(v.z & 0xffff0000u);
      a6 += w * __uint_as_float(v.w << 16);
      a7 += w * __uint_as_float(v.w & 0xffff0000u);
    }
  }

  // fold the two halves (edge-interleave), then per-head normalize
  denom += __shfl_xor(denom, 32);
  a0 += __shfl_xor(a0, 32); a1 += __shfl_xor(a1, 32);
  a2 += __shfl_xor(a2, 32); a3 += __shfl_xor(a3, 32);
  a4 += __shfl_xor(a4, 32); a5 += __shfl_xor(a5, 32);
  a6 += __shfl_xor(a6, 32); a7 += __shfl_xor(a7, 32);
  float inv = 1.f / denom;
  a0 *= inv; a1 *= inv; a2 *= inv; a3 *= inv;
  a4 *= inv; a5 *= inv; a6 *= inv; a7 *= inv;

  // head mean: channel (l31&7)*8+j lives at lanes {l31&7, +8, +16, +24}
  a0 += __shfl_xor(a0, 8); a0 += __shfl_xor(a0, 16);
  a1 += __shfl_xor(a1, 8); a1 += __shfl_xor(a1, 16);
  a2 += __shfl_xor(a2, 8); a2 += __shfl_xor(a2, 16);
  a3 += __shfl_xor(a3, 8); a3 += __shfl_xor(a3, 16);
  a4 += __shfl_xor(a4, 8); a4 += __shfl_xor(a4, 16);
  a5 += __shfl_xor(a5, 8); a5 += __shfl_xor(a5, 16);
  a6 += __shfl_xor(a6, 8); a6 += __shfl_xor(a6, 16);
  a7 += __shfl_xor(a7, 8); a7 += __shfl_xor(a7, 16);

  if (lane < 8) {
    const float* bp = bias + lane * 8;
    float4 b0 = *(const float4*)(bp);
    float4 b1 = *(const float4*)(bp + 4);
    ushort4 o0, o1;
    o0.x = f2bf(fmaxf(0.25f * a0 + b0.x, 0.f));
    o0.y = f2bf(fmaxf(0.25f * a1 + b0.y, 0.f));
    o0.z = f2bf(fmaxf(0.25f * a2 + b0.z, 0.f));
    o0.w = f2bf(fmaxf(0.25f * a3 + b0.w, 0.f));
    o1.x = f2bf(fmaxf(0.25f * a4 + b1.x, 0.f));
    o1.y = f2bf(fmaxf(0.25f * a5 + b1.y, 0.f));
    o1.z = f2bf(fmaxf(0.25f * a6 + b1.z, 0.f));
    o1.w = f2bf(fmaxf(0.25f * a7 + b1.w, 0.f));
    unsigned short* op = hout + (size_t)node * 64 + lane * 8;
    *(ushort4*)(op) = o0;
    *(ushort4*)(op + 4) = o1;
  }
}

// ---------------- global mean pool (batch is sorted), bf16 in ----------------
__global__ void pool_kernel(const unsigned short* __restrict__ h, const int* __restrict__ batch,
                            float* __restrict__ pool, float* __restrict__ pcnt, int n_nodes) {
  int c = threadIdx.x;  // 64 threads
  int n0 = blockIdx.x * 64;
  int n1 = min(n0 + 64, n_nodes);
  float acc = 0.f;
  int run = 0;
  int gcur = batch[n0];
  for (int n = n0; n < n1; ++n) {
    int g = batch[n];
    if (g != gcur) {
      atomicAdd(&pool[gcur * 64 + c], acc);
      if (c == 0) atomicAdd(&pcnt[gcur], (float)run);
      acc = 0.f; run = 0; gcur = g;
    }
    acc += bf2f(h[(size_t)n * 64 + c]);
    ++run;
  }
  atomicAdd(&pool[gcur * 64 + c], acc);
  if (c == 0) atomicAdd(&pcnt[gcur], (float)run);
}

// ---------------- out = (pool/cnt) @ Wo + bo : [G,64]@[64,32] ----------------
__global__ void out_kernel(const float* __restrict__ pool, const float* __restrict__ pcnt,
                           const float* __restrict__ Wo, const float* __restrict__ bo,
                           float* __restrict__ out, int g_total) {
  int idx = blockIdx.x * blockDim.x + threadIdx.x;
  if (idx >= g_total * 32) return;
  int g = idx >> 5, d = idx & 31;
  float inv = 1.f / fmaxf(pcnt[g], 1.f);
  float acc = bo[d];
#pragma unroll
  for (int c = 0; c < 64; ++c) acc += (pool[g * 64 + c] * inv) * Wo[c * 32 + d];
  out[idx] = acc;
}

extern "C" void kernel_launch(void* const* d_in, const int* in_sizes, int n_in,
                              void* d_out, int out_size, void* d_ws, size_t ws_size,
                              hipStream_t stream) {
  const float* x     = (const float*)d_in[0];
  const int*   ei    = (const int*)d_in[1];
  const int*   batch = (const int*)d_in[2];
  const float* Wp    = (const float*)d_in[3];
  const float* bp    = (const float*)d_in[4];
  const float* Wo    = (const float*)d_in[5];
  const float* bo    = (const float*)d_in[6];
  const float* Wl[3]  = {(const float*)d_in[7],  (const float*)d_in[11], (const float*)d_in[15]};
  const float* Asl[3] = {(const float*)d_in[8],  (const float*)d_in[12], (const float*)d_in[16]};
  const float* Adl[3] = {(const float*)d_in[9],  (const float*)d_in[13], (const float*)d_in[17]};
  const float* Bl[3]  = {(const float*)d_in[10], (const float*)d_in[14], (const float*)d_in[18]};

  const int N = in_sizes[0] / 16;   // 50000
  const int E = in_sizes[1] / 2;    // 800000
  const int G = out_size / 32;      // 64
  const int Et = E + N;             // edges incl. self loops
  const int* src = ei;
  const int* dst = ei + E;
  const int NB = (N + 1023) / 1024; // scan blocks (<=64)

  // workspace carve (256B aligned)
  char* ws = (char*)d_ws;
  size_t off = 0;
  auto take = [&](size_t bytes) -> void* {
    void* p = ws + off;
    off = (off + bytes + 255) & ~(size_t)255;
    return p;
  };
  unsigned short* h_a = (unsigned short*)take((size_t)N * 64 * 2);
  unsigned short* h_b = (unsigned short*)take((size_t)N * 64 * 2);
  unsigned short* hwb = (unsigned short*)take((size_t)N * 256 * 2);
  float* alS   = (float*)take((size_t)N * 4 * 4);
  float* alD   = (float*)take((size_t)N * 4 * 4);
  int*   deg   = (int*)take((size_t)N * 4);
  int*   cnt   = (int*)take((size_t)N * 4);
  int*   rowp  = (int*)take((size_t)(N + 1) * 4);
  int*   col   = (int*)take((size_t)Et * 4);
  int*   bsum  = (int*)take((size_t)64 * 4);
  int*   bpre  = (int*)take((size_t)65 * 4);
  unsigned short* Wsw  = (unsigned short*)take((size_t)3 * 16384 * 2);
  unsigned short* Wasw = (unsigned short*)take((size_t)3 * 1024 * 2);
  float* pool  = (float*)take((size_t)G * 64 * 4);
  float* pcnt  = (float*)take((size_t)G * 4);
  (void)ws_size; (void)n_in;

  // fold attention vectors + swizzle weights (one fused launch)
  prep_kernel<<<3, 256, 0, stream>>>(Wl[0], Asl[0], Adl[0], Wl[1], Asl[1], Adl[1],
                                     Wl[2], Asl[2], Adl[2], Wsw, Wasw);

  // CSR build (self-loop +1 folded into scan_a; init_csr folded into scan_c)
  hipMemsetAsync(deg, 0, (size_t)N * 4, stream);
  hist_kernel<<<(E + 255) / 256, 256, 0, stream>>>(dst, deg, E);
  scan_a<<<NB, 256, 0, stream>>>(deg, rowp, bsum, N);
  scan_b<<<1, 64, 0, stream>>>(bsum, bpre, NB);
  scan_c<<<(N + 255) / 256, 256, 0, stream>>>(rowp, bpre, cnt, col, N);
  scatter_kernel<<<(E + 255) / 256, 256, 0, stream>>>(src, dst, rowp, cnt, col, E);

  // input projection
  proj_kernel<<<((size_t)N * 64 + 255) / 256, 256, 0, stream>>>(x, Wp, bp, h_a, N);

  // 3 GAT layers
  const unsigned short* hin = h_a;
  unsigned short* hout = h_b;
  for (int l = 0; l < 3; ++l) {
    hw_kernel<<<(N + 63) / 64, 256, 0, stream>>>(hin, Wsw + (size_t)l * 16384,
                                                 Wasw + (size_t)l * 1024, hwb, alS, alD, N);
    gat_agg<<<(N + 3) / 4, 256, 0, stream>>>(rowp, col, alS, alD, hwb, Bl[l], hout, N);
    const unsigned short* tmp = hout;
    hout = (unsigned short*)hin;
    hin = tmp;
  }

  // pooling + output projection (single memset covers pool..pcnt span)
  hipMemsetAsync(pool, 0, (size_t)((char*)(pcnt + G) - (char*)pool), stream);
  pool_kernel<<<(N + 63) / 64, 64, 0, stream>>>(hin, batch, pool, pcnt, N);
  out_kernel<<<(G * 32 + 255) / 256, 256, 0, stream>>>(pool, pcnt, Wo, bo, (float*)d_out, G);
}

// Round 10
// 406.307 us; speedup vs baseline: 2.5372x; 1.0101x over previous
//
#include <hip/hip_runtime.h>

#define NEG_SLOPE 0.2f

typedef __attribute__((ext_vector_type(8))) short bf16x8;
typedef __attribute__((ext_vector_type(8))) unsigned short u16x8;
typedef __attribute__((ext_vector_type(4))) float f32x4;

__device__ __forceinline__ float lrelu(float x) { return fmaxf(x, NEG_SLOPE * x); }

__device__ __forceinline__ float bf2f(unsigned short u) {
  return __uint_as_float(((unsigned int)u) << 16);
}
__device__ __forceinline__ unsigned short f2bf(float f) {
  unsigned int u = __float_as_uint(f);
  u += 0x7fffu + ((u >> 16) & 1u);   // round-to-nearest-even
  return (unsigned short)(u >> 16);
}

// ---------------- h0 = relu(x @ Wp + bp) : [N,16]@[16,64], bf16 out ----------------
__global__ void proj_kernel(const float* __restrict__ x, const float* __restrict__ Wp,
                            const float* __restrict__ bp, unsigned short* __restrict__ h,
                            int n_nodes) {
  int idx = blockIdx.x * blockDim.x + threadIdx.x;
  int n = idx >> 6, c = idx & 63;
  if (n >= n_nodes) return;
  float acc = bp[c];
#pragma unroll
  for (int k = 0; k < 16; ++k) acc += x[n * 16 + k] * Wp[k * 64 + c];
  h[n * 64 + c] = f2bf(fmaxf(acc, 0.f));
}

// ---------------- CSR build (by destination), self-loop first ----------------
__global__ void hist_kernel(const int* __restrict__ dst, int* __restrict__ deg, int e) {
  int i = blockIdx.x * blockDim.x + threadIdx.x;
  if (i < e) atomicAdd(&deg[dst[i]], 1);
}

// phase A: per-block (1024 elems) local exclusive scan of (deg[i]+1); block sums out.
__global__ __launch_bounds__(256) void scan_a(const int* __restrict__ deg, int* __restrict__ rowp,
                                              int* __restrict__ bsum, int n) {
  __shared__ int s[256];
  int t = threadIdx.x;
  int base = blockIdx.x * 1024 + t * 4;
  int d0 = (base + 0 < n) ? deg[base + 0] + 1 : 0;
  int d1 = (base + 1 < n) ? deg[base + 1] + 1 : 0;
  int d2 = (base + 2 < n) ? deg[base + 2] + 1 : 0;
  int d3 = (base + 3 < n) ? deg[base + 3] + 1 : 0;
  s[t] = d0 + d1 + d2 + d3;
  __syncthreads();
  for (int off = 1; off < 256; off <<= 1) {
    int v = 0;
    if (t >= off) v = s[t - off];
    __syncthreads();
    if (t >= off) s[t] += v;
    __syncthreads();
  }
  int p = (t == 0) ? 0 : s[t - 1];
  if (base + 0 < n) rowp[base + 0] = p;
  p += d0;
  if (base + 1 < n) rowp[base + 1] = p;
  p += d1;
  if (base + 2 < n) rowp[base + 2] = p;
  p += d2;
  if (base + 3 < n) rowp[base + 3] = p;
  if (t == 255) bsum[blockIdx.x] = s[255];
}

// phase B: single wave exclusive-scans <=64 block sums; bpre[64] = grand total.
__global__ void scan_b(const int* __restrict__ bsum, int* __restrict__ bpre, int nb) {
  int t = threadIdx.x;  // 64 threads = 1 wave
  int v = (t < nb) ? bsum[t] : 0;
  int orig = v;
#pragma unroll
  for (int off = 1; off < 64; off <<= 1) {
    int u = __shfl_up(v, off);
    if (t >= off) v += u;
  }
  bpre[t] = v - orig;
  if (t == 63) bpre[64] = v;
}

// phase C: add block prefixes; fused init_csr (self-loop slot 0).
__global__ void scan_c(int* __restrict__ rowp, const int* __restrict__ bpre,
                       int* __restrict__ cnt, int* __restrict__ col, int n) {
  int i = blockIdx.x * blockDim.x + threadIdx.x;
  if (i < n) {
    int r = rowp[i] + bpre[i >> 10];
    rowp[i] = r;
    cnt[i] = 1;       // slot 0 = self loop
    col[r] = i;
  }
  if (i == 0) rowp[n] = bpre[64];
}

__global__ void scatter_kernel(const int* __restrict__ src, const int* __restrict__ dst,
                               const int* __restrict__ rowp, int* __restrict__ cnt,
                               int* __restrict__ col, int e) {
  int i = blockIdx.x * blockDim.x + threadIdx.x;
  if (i < e) {
    int d = dst[i];
    int pos = rowp[d] + atomicAdd(&cnt[d], 1);
    col[pos] = src[i];
  }
}

// ---------------- fused: fold a_src/a_dst into W, then swizzle W & Wa to MFMA B-frag (bf16) ----
__global__ __launch_bounds__(256) void prep_kernel(
    const float* __restrict__ W0, const float* __restrict__ as0, const float* __restrict__ ad0,
    const float* __restrict__ W1, const float* __restrict__ as1, const float* __restrict__ ad1,
    const float* __restrict__ W2, const float* __restrict__ as2, const float* __restrict__ ad2,
    unsigned short* __restrict__ Wsw, unsigned short* __restrict__ Wasw) {
  __shared__ float wa[512];
  int l = blockIdx.x;
  const float* W  = l == 0 ? W0  : l == 1 ? W1  : W2;
  const float* as = l == 0 ? as0 : l == 1 ? as1 : as2;
  const float* ad = l == 0 ? ad0 : l == 1 ? ad1 : ad2;
  int t = threadIdx.x;          // 256 threads
  {
    int k = t >> 2, h = t & 3;
    float ss = 0.f, sd = 0.f;
    for (int c = 0; c < 64; ++c) {
      float w = W[k * 256 + h * 64 + c];
      ss += w * as[h * 64 + c];
      sd += w * ad[h * 64 + c];
    }
    wa[k * 8 + h] = ss;
    wa[k * 8 + 4 + h] = sd;
  }
  __syncthreads();
  for (int s = t; s < 2048; s += 256) {
    int nt = s >> 7, kk = (s >> 6) & 1, lane = s & 63;
    int kq = lane >> 4, r = lane & 15;
#pragma unroll
    for (int j = 0; j < 8; ++j) {
      int k = kk * 32 + kq * 8 + j;
      Wsw[(size_t)l * 16384 + (size_t)s * 8 + j] = f2bf(W[k * 256 + nt * 16 + r]);
    }
  }
  if (t < 128) {
    int lane = t & 63, kq = lane >> 4, r = lane & 15;
    int kk = t >> 6;
#pragma unroll
    for (int j = 0; j < 8; ++j) {
      int k = kk * 32 + kq * 8 + j;
      float v = (r < 8) ? wa[k * 8 + r] : 0.f;
      Wasw[l * 1024 + t * 8 + j] = f2bf(v);
    }
  }
}

// ---------------- hw(bf16) = h @ W via MFMA + attention logits ----------------
// Epilogue: stage bf16 results in LDS (padded rows), then coalesced 16B row-streaming stores.
__global__ __launch_bounds__(256) void hw_kernel(const unsigned short* __restrict__ hb,
                                                 const unsigned short* __restrict__ Wsw,
                                                 const unsigned short* __restrict__ Wasw,
                                                 unsigned short* __restrict__ hwb,
                                                 float* __restrict__ al_s, float* __restrict__ al_d,
                                                 int n_nodes) {
  __shared__ unsigned short st[64][264];   // 256 cols + 8 pad (keeps 16B align, spreads banks)
  int t = threadIdx.x;
  int w = t >> 6, lane = t & 63;
  int kq = lane >> 4, r16 = lane & 15;
  int n0 = blockIdx.x << 6;

  // A fragments: 4 m-tiles x 2 k-steps; direct 16B loads from row-major bf16 h
  bf16x8 a[4][2];
#pragma unroll
  for (int m = 0; m < 4; ++m) {
    int row = min(n0 + m * 16 + r16, n_nodes - 1);
    const unsigned short* p = hb + (size_t)row * 64 + kq * 8;
    a[m][0] = *(const bf16x8*)(p);
    a[m][1] = *(const bf16x8*)(p + 32);
  }
  // B fragments: 4 local n-tiles x 2 k-steps
  bf16x8 b[4][2];
#pragma unroll
  for (int nt = 0; nt < 4; ++nt) {
    int ntg = w * 4 + nt;
    const unsigned short* p = Wsw + ((size_t)ntg * 128 + lane) * 8;
    b[nt][0] = *(const bf16x8*)(p);
    b[nt][1] = *(const bf16x8*)(p + 512);
  }

  f32x4 acc[4][4];
#pragma unroll
  for (int m = 0; m < 4; ++m)
#pragma unroll
    for (int nt = 0; nt < 4; ++nt) acc[m][nt] = (f32x4){0.f, 0.f, 0.f, 0.f};

#pragma unroll
  for (int m = 0; m < 4; ++m)
#pragma unroll
    for (int nt = 0; nt < 4; ++nt) {
      acc[m][nt] = __builtin_amdgcn_mfma_f32_16x16x32_bf16(a[m][0], b[nt][0], acc[m][nt], 0, 0, 0);
      acc[m][nt] = __builtin_amdgcn_mfma_f32_16x16x32_bf16(a[m][1], b[nt][1], acc[m][nt], 0, 0, 0);
    }

  // stage C into LDS (C/D mapping: col=lane&15, row=(lane>>4)*4+reg)
#pragma unroll
  for (int m = 0; m < 4; ++m)
#pragma unroll
    for (int j = 0; j < 4; ++j) {
      int row = m * 16 + kq * 4 + j;
#pragma unroll
      for (int nt = 0; nt < 4; ++nt)
        st[row][(w * 4 + nt) * 16 + r16] = f2bf(acc[m][nt][j]);
    }
  __syncthreads();

  // coalesced stores: each instr = 32 lanes x 16B = one full 512B row; wave does 2 rows/iter
  int rmax = min(64, n_nodes - n0);
  for (int i = t; i < (rmax << 5); i += 256) {
    int row = i >> 5, ch = i & 31;
    *(u16x8*)(hwb + (size_t)(n0 + row) * 256 + ch * 8) = *(const u16x8*)(&st[row][ch * 8]);
  }

  // attention logits: wave w handles m-tile w; B = folded Wa (8 valid cols)
  bf16x8 ba0 = *(const bf16x8*)(Wasw + lane * 8);
  bf16x8 ba1 = *(const bf16x8*)(Wasw + (64 + lane) * 8);
  f32x4 accl = (f32x4){0.f, 0.f, 0.f, 0.f};
  accl = __builtin_amdgcn_mfma_f32_16x16x32_bf16(a[w][0], ba0, accl, 0, 0, 0);
  accl = __builtin_amdgcn_mfma_f32_16x16x32_bf16(a[w][1], ba1, accl, 0, 0, 0);
  if (r16 < 8) {
#pragma unroll
    for (int j = 0; j < 4; ++j) {
      int row = n0 + w * 16 + kq * 4 + j;
      if (row < n_nodes) {
        if (r16 < 4) al_s[row * 4 + r16] = accl[j];
        else         al_d[row * 4 + (r16 - 4)] = accl[j];
      }
    }
  }
}

// ---------------- aggregate: wave per node, two edges per iteration ----------------
__global__ __launch_bounds__(256) void gat_agg(const int* __restrict__ rowp, const int* __restrict__ col,
                                               const float* __restrict__ alS, const float* __restrict__ alD,
                                               const unsigned short* __restrict__ hwb,
                                               const float* __restrict__ bias,
                                               unsigned short* __restrict__ hout,
                                               int n_nodes) {
  __shared__ uint2 pw[4][64 * 4];   // [wave][edge*4 + head] = (byte addr, w)
  int t = threadIdx.x;
  int wslot = t >> 6, lane = t & 63;
  int node = blockIdx.x * 4 + wslot;
  if (node >= n_nodes) return;      // whole wave exits together
  int base = rowp[node];
  int degv = rowp[node + 1] - base;
  int l31 = lane & 31;
  int half = lane >> 5;                               // which edge of the pair
  int headw = l31 >> 3;                               // head owning this lane's 8 channels
  unsigned int laneoff = (unsigned int)l31 << 4;      // 16B per lane within 512B row
  float4 ald4 = *(const float4*)(alD + (size_t)node * 4);

  float a0 = 0.f, a1 = 0.f, a2 = 0.f, a3 = 0.f;
  float a4 = 0.f, a5 = 0.f, a6 = 0.f, a7 = 0.f, denom = 0.f;

  for (int c0 = 0; c0 < degv; c0 += 64) {
    int cnt = min(64, degv - c0);
    {
      unsigned int ab = 0u;
      float w0 = 0.f, w1 = 0.f, w2 = 0.f, w3 = 0.f;
      if (lane < cnt) {
        int s = col[base + c0 + lane];                // coalesced
        float4 as4 = *(const float4*)(alS + (size_t)s * 4);
        ab = (unsigned int)s << 9;                    // byte addr of hwb row
        w0 = __expf(lrelu(as4.x + ald4.x));
        w1 = __expf(lrelu(as4.y + ald4.y));
        w2 = __expf(lrelu(as4.z + ald4.z));
        w3 = __expf(lrelu(as4.w + ald4.w));
      }
      uint4* pd = (uint4*)&pw[wslot][lane * 4];
      pd[0] = make_uint4(ab, __float_as_uint(w0), ab, __float_as_uint(w1));
      pd[1] = make_uint4(ab, __float_as_uint(w2), ab, __float_as_uint(w3));
    }
    // wave-synchronous: same wave wrote, same wave reads (lgkmcnt auto-inserted)
    int iters = (cnt + 1) >> 1;
#pragma unroll 4
    for (int i = 0; i < iters; ++i) {
      int e = i * 2 + half;
      uint2 p = pw[wslot][e * 4 + headw];             // one ds_read_b64
      float w = __uint_as_float(p.y);
      uint4 v = *(const uint4*)((const char*)hwb + (p.x + laneoff));  // independent gather
      denom += w;
      a0 += w * __uint_as_float(v.x << 16);
      a1 += w * __uint_as_float(v.x & 0xffff0000u);
      a2 += w * __uint_as_float(v.y << 16);
      a3 += w * __uint_as_float(v.y & 0xffff0000u);
      a4 += w * __uint_as_float(v.z << 16);
      a5 += w * __uint_as_float(v.z & 0xffff0000u);
      a6 += w * __uint_as_float(v.w << 16);
      a7 += w * __uint_as_float(v.w & 0xffff0000u);
    }
  }

  // fold the two halves (edge-interleave), then per-head normalize
  denom += __shfl_xor(denom, 32);
  a0 += __shfl_xor(a0, 32); a1 += __shfl_xor(a1, 32);
  a2 += __shfl_xor(a2, 32); a3 += __shfl_xor(a3, 32);
  a4 += __shfl_xor(a4, 32); a5 += __shfl_xor(a5, 32);
  a6 += __shfl_xor(a6, 32); a7 += __shfl_xor(a7, 32);
  float inv = 1.f / denom;
  a0 *= inv; a1 *= inv; a2 *= inv; a3 *= inv;
  a4 *= inv; a5 *= inv; a6 *= inv; a7 *= inv;

  // head mean: channel (l31&7)*8+j lives at lanes {l31&7, +8, +16, +24}
  a0 += __shfl_xor(a0, 8); a0 += __shfl_xor(a0, 16);
  a1 += __shfl_xor(a1, 8); a1 += __shfl_xor(a1, 16);
  a2 += __shfl_xor(a2, 8); a2 += __shfl_xor(a2, 16);
  a3 += __shfl_xor(a3, 8); a3 += __shfl_xor(a3, 16);
  a4 += __shfl_xor(a4, 8); a4 += __shfl_xor(a4, 16);
  a5 += __shfl_xor(a5, 8); a5 += __shfl_xor(a5, 16);
  a6 += __shfl_xor(a6, 8); a6 += __shfl_xor(a6, 16);
  a7 += __shfl_xor(a7, 8); a7 += __shfl_xor(a7, 16);

  if (lane < 8) {
    const float* bp = bias + lane * 8;
    float4 b0 = *(const float4*)(bp);
    float4 b1 = *(const float4*)(bp + 4);
    ushort4 o0, o1;
    o0.x = f2bf(fmaxf(0.25f * a0 + b0.x, 0.f));
    o0.y = f2bf(fmaxf(0.25f * a1 + b0.y, 0.f));
    o0.z = f2bf(fmaxf(0.25f * a2 + b0.z, 0.f));
    o0.w = f2bf(fmaxf(0.25f * a3 + b0.w, 0.f));
    o1.x = f2bf(fmaxf(0.25f * a4 + b1.x, 0.f));
    o1.y = f2bf(fmaxf(0.25f * a5 + b1.y, 0.f));
    o1.z = f2bf(fmaxf(0.25f * a6 + b1.z, 0.f));
    o1.w = f2bf(fmaxf(0.25f * a7 + b1.w, 0.f));
    unsigned short* op = hout + (size_t)node * 64 + lane * 8;
    *(ushort4*)(op) = o0;
    *(ushort4*)(op + 4) = o1;
  }
}

// ---------------- global mean pool (batch is sorted), bf16 in ----------------
__global__ void pool_kernel(const unsigned short* __restrict__ h, const int* __restrict__ batch,
                            float* __restrict__ pool, float* __restrict__ pcnt, int n_nodes) {
  int c = threadIdx.x;  // 64 threads
  int n0 = blockIdx.x * 64;
  int n1 = min(n0 + 64, n_nodes);
  float acc = 0.f;
  int run = 0;
  int gcur = batch[n0];
  for (int n = n0; n < n1; ++n) {
    int g = batch[n];
    if (g != gcur) {
      atomicAdd(&pool[gcur * 64 + c], acc);
      if (c == 0) atomicAdd(&pcnt[gcur], (float)run);
      acc = 0.f; run = 0; gcur = g;
    }
    acc += bf2f(h[(size_t)n * 64 + c]);
    ++run;
  }
  atomicAdd(&pool[gcur * 64 + c], acc);
  if (c == 0) atomicAdd(&pcnt[gcur], (float)run);
}

// ---------------- out = (pool/cnt) @ Wo + bo : [G,64]@[64,32] ----------------
__global__ void out_kernel(const float* __restrict__ pool, const float* __restrict__ pcnt,
                           const float* __restrict__ Wo, const float* __restrict__ bo,
                           float* __restrict__ out, int g_total) {
  int idx = blockIdx.x * blockDim.x + threadIdx.x;
  if (idx >= g_total * 32) return;
  int g = idx >> 5, d = idx & 31;
  float inv = 1.f / fmaxf(pcnt[g], 1.f);
  float acc = bo[d];
#pragma unroll
  for (int c = 0; c < 64; ++c) acc += (pool[g * 64 + c] * inv) * Wo[c * 32 + d];
  out[idx] = acc;
}

extern "C" void kernel_launch(void* const* d_in, const int* in_sizes, int n_in,
                              void* d_out, int out_size, void* d_ws, size_t ws_size,
                              hipStream_t stream) {
  const float* x     = (const float*)d_in[0];
  const int*   ei    = (const int*)d_in[1];
  const int*   batch = (const int*)d_in[2];
  const float* Wp    = (const float*)d_in[3];
  const float* bp    = (const float*)d_in[4];
  const float* Wo    = (const float*)d_in[5];
  const float* bo    = (const float*)d_in[6];
  const float* Wl[3]  = {(const float*)d_in[7],  (const float*)d_in[11], (const float*)d_in[15]};
  const float* Asl[3] = {(const float*)d_in[8],  (const float*)d_in[12], (const float*)d_in[16]};
  const float* Adl[3] = {(const float*)d_in[9],  (const float*)d_in[13], (const float*)d_in[17]};
  const float* Bl[3]  = {(const float*)d_in[10], (const float*)d_in[14], (const float*)d_in[18]};

  const int N = in_sizes[0] / 16;   // 50000
  const int E = in_sizes[1] / 2;    // 800000
  const int G = out_size / 32;      // 64
  const int Et = E + N;             // edges incl. self loops
  const int* src = ei;
  const int* dst = ei + E;
  const int NB = (N + 1023) / 1024; // scan blocks (<=64)

  // workspace carve (256B aligned)
  char* ws = (char*)d_ws;
  size_t off = 0;
  auto take = [&](size_t bytes) -> void* {
    void* p = ws + off;
    off = (off + bytes + 255) & ~(size_t)255;
    return p;
  };
  unsigned short* h_a = (unsigned short*)take((size_t)N * 64 * 2);
  unsigned short* h_b = (unsigned short*)take((size_t)N * 64 * 2);
  unsigned short* hwb = (unsigned short*)take((size_t)N * 256 * 2);
  float* alS   = (float*)take((size_t)N * 4 * 4);
  float* alD   = (float*)take((size_t)N * 4 * 4);
  int*   deg   = (int*)take((size_t)N * 4);
  int*   cnt   = (int*)take((size_t)N * 4);
  int*   rowp  = (int*)take((size_t)(N + 1) * 4);
  int*   col   = (int*)take((size_t)Et * 4);
  int*   bsum  = (int*)take((size_t)64 * 4);
  int*   bpre  = (int*)take((size_t)65 * 4);
  unsigned short* Wsw  = (unsigned short*)take((size_t)3 * 16384 * 2);
  unsigned short* Wasw = (unsigned short*)take((size_t)3 * 1024 * 2);
  float* pool  = (float*)take((size_t)G * 64 * 4);
  float* pcnt  = (float*)take((size_t)G * 4);
  (void)ws_size; (void)n_in;

  // fold attention vectors + swizzle weights (one fused launch)
  prep_kernel<<<3, 256, 0, stream>>>(Wl[0], Asl[0], Adl[0], Wl[1], Asl[1], Adl[1],
                                     Wl[2], Asl[2], Adl[2], Wsw, Wasw);

  // CSR build (self-loop +1 folded into scan_a; init_csr folded into scan_c)
  hipMemsetAsync(deg, 0, (size_t)N * 4, stream);
  hist_kernel<<<(E + 255) / 256, 256, 0, stream>>>(dst, deg, E);
  scan_a<<<NB, 256, 0, stream>>>(deg, rowp, bsum, N);
  scan_b<<<1, 64, 0, stream>>>(bsum, bpre, NB);
  scan_c<<<(N + 255) / 256, 256, 0, stream>>>(rowp, bpre, cnt, col, N);
  scatter_kernel<<<(E + 255) / 256, 256, 0, stream>>>(src, dst, rowp, cnt, col, E);

  // input projection
  proj_kernel<<<((size_t)N * 64 + 255) / 256, 256, 0, stream>>>(x, Wp, bp, h_a, N);

  // 3 GAT layers
  const unsigned short* hin = h_a;
  unsigned short* hout = h_b;
  for (int l = 0; l < 3; ++l) {
    hw_kernel<<<(N + 63) / 64, 256, 0, stream>>>(hin, Wsw + (size_t)l * 16384,
                                                 Wasw + (size_t)l * 1024, hwb, alS, alD, N);
    gat_agg<<<(N + 3) / 4, 256, 0, stream>>>(rowp, col, alS, alD, hwb, Bl[l], hout, N);
    const unsigned short* tmp = hout;
    hout = (unsigned short*)hin;
    hin = tmp;
  }

  // pooling + output projection (single memset covers pool..pcnt span)
  hipMemsetAsync(pool, 0, (size_t)((char*)(pcnt + G) - (char*)pool), stream);
  pool_kernel<<<(N + 63) / 64, 64, 0, stream>>>(hin, batch, pool, pcnt, N);
  out_kernel<<<(G * 32 + 255) / 256, 256, 0, stream>>>(pool, pcnt, Wo, bo, (float*)d_out, G);
}